// Round 1
// baseline (1003.458 us; speedup 1.0000x reference)
//
#include <hip/hip_runtime.h>
#include <cstdint>
#include <cstddef>

// ---------------------------------------------------------------------------
// Types / helpers
// ---------------------------------------------------------------------------
typedef __bf16 bf16x8 __attribute__((ext_vector_type(8)));
typedef float  floatx4 __attribute__((ext_vector_type(4)));

__device__ __forceinline__ uint16_t f2b(float f) {
    uint32_t u = __builtin_bit_cast(uint32_t, f);
    return (uint16_t)((u + 0x7fffu + ((u >> 16) & 1)) >> 16);  // RNE
}

__device__ __forceinline__ void gload_lds16(const void* g, void* l) {
    // async 16B/lane global->LDS; LDS dest = wave-uniform base + lane*16
    __builtin_amdgcn_global_load_lds(
        (__attribute__((address_space(1))) void*)(void*)g,
        (__attribute__((address_space(3))) void*)l, 16, 0, 0);
}

// ---------------------------------------------------------------------------
// Weight repack kernels (fp32 -> bf16, transposed to [N][K])
// ---------------------------------------------------------------------------
// Wq/Wk/Wv: [H][1024][64] -> rows (m*1024 + h*64 + hd) of Wqkv_t[3072][1024]
__global__ __launch_bounds__(256) void repack_qkv(
    const float* __restrict__ Wq, const float* __restrict__ Wk,
    const float* __restrict__ Wv, uint16_t* __restrict__ out)
{
    __shared__ uint16_t tile[32][33];
    const int m = blockIdx.z >> 4, h = blockIdx.z & 15;
    const float* W = (m == 0) ? Wq : (m == 1) ? Wk : Wv;
    const float* src = W + (size_t)h * 1024 * 64;           // [1024][64]
    const int d0 = blockIdx.x * 32, hd0 = blockIdx.y * 32;
    const int tx = threadIdx.x & 31, ty = threadIdx.x >> 5;
#pragma unroll
    for (int i = 0; i < 4; ++i)
        tile[ty + i * 8][tx] = f2b(src[(size_t)(d0 + ty + i * 8) * 64 + hd0 + tx]);
    __syncthreads();
    uint16_t* dst = out + (size_t)(m * 1024 + h * 64) * 1024; // [64][1024]
#pragma unroll
    for (int i = 0; i < 4; ++i)
        dst[(size_t)(hd0 + ty + i * 8) * 1024 + d0 + tx] = tile[tx][ty + i * 8];
}

// generic: in [R][C] fp32 -> out [C][R] bf16
__global__ __launch_bounds__(256) void transpose_f2b(
    const float* __restrict__ in, uint16_t* __restrict__ out, int R, int C)
{
    __shared__ uint16_t tile[32][33];
    const int c0 = blockIdx.x * 32, r0 = blockIdx.y * 32;
    const int tx = threadIdx.x & 31, ty = threadIdx.x >> 5;
#pragma unroll
    for (int i = 0; i < 4; ++i)
        tile[ty + i * 8][tx] = f2b(in[(size_t)(r0 + ty + i * 8) * C + c0 + tx]);
    __syncthreads();
#pragma unroll
    for (int i = 0; i < 4; ++i)
        out[(size_t)(c0 + ty + i * 8) * R + r0 + tx] = tile[tx][ty + i * 8];
}

__global__ void concat_bias(const float* __restrict__ bq, const float* __restrict__ bk,
                            const float* __restrict__ bv, float* __restrict__ out)
{
    int i = blockIdx.x * 256 + threadIdx.x;  // 3072 total
    out[i] = (i < 1024) ? bq[i] : (i < 2048) ? bk[i - 1024] : bv[i - 2048];
}

// V slice of qkv [B*T][3072] (cols 2048+h*64+hd) -> Vt [(b*16+h)*64+hd][2048]
__global__ __launch_bounds__(256) void transpose_v(
    const uint16_t* __restrict__ qkv, uint16_t* __restrict__ Vt)
{
    __shared__ uint16_t tile[32][33];
    const int bh = blockIdx.z;
    const int b = bh >> 4, h = bh & 15;
    const int t0 = blockIdx.x * 32, hd0 = blockIdx.y * 32;
    const int tx = threadIdx.x & 31, ty = threadIdx.x >> 5;
    const uint16_t* src = qkv + (size_t)b * 2048 * 3072 + 2048 + h * 64;
#pragma unroll
    for (int i = 0; i < 4; ++i)
        tile[ty + i * 8][tx] = src[(size_t)(t0 + ty + i * 8) * 3072 + hd0 + tx];
    __syncthreads();
    uint16_t* dst = Vt + (size_t)bh * 64 * 2048;
#pragma unroll
    for (int i = 0; i < 4; ++i)
        dst[(size_t)(hd0 + ty + i * 8) * 2048 + t0 + tx] = tile[tx][ty + i * 8];
}

// ---------------------------------------------------------------------------
// LayerNorm: fp32 [rows][1024] -> bf16, one block per row
// ---------------------------------------------------------------------------
__global__ __launch_bounds__(256) void ln_bf16(
    const float* __restrict__ x, const float* __restrict__ g,
    const float* __restrict__ b, uint16_t* __restrict__ out)
{
    const int row = blockIdx.x;
    const int t = threadIdx.x;
    const float4 v = ((const float4*)(x + (size_t)row * 1024))[t];
    float s  = v.x + v.y + v.z + v.w;
    float s2 = v.x * v.x + v.y * v.y + v.z * v.z + v.w * v.w;
#pragma unroll
    for (int o = 32; o > 0; o >>= 1) { s += __shfl_down(s, o); s2 += __shfl_down(s2, o); }
    __shared__ float red[8];
    const int wave = t >> 6, lane = t & 63;
    if (lane == 0) { red[wave] = s; red[4 + wave] = s2; }
    __syncthreads();
    if (t == 0) {
        float a  = red[0] + red[1] + red[2] + red[3];
        float a2 = red[4] + red[5] + red[6] + red[7];
        float mu = a * (1.0f / 1024.0f);
        red[0] = mu;
        red[4] = rsqrtf(a2 * (1.0f / 1024.0f) - mu * mu + 1e-5f);
    }
    __syncthreads();
    const float mu = red[0], rs = red[4];
    const float4 gv = ((const float4*)g)[t];
    const float4 bv = ((const float4*)b)[t];
    ushort4 ov;
    ov.x = f2b((v.x - mu) * rs * gv.x + bv.x);
    ov.y = f2b((v.y - mu) * rs * gv.y + bv.y);
    ov.z = f2b((v.z - mu) * rs * gv.z + bv.z);
    ov.w = f2b((v.w - mu) * rs * gv.w + bv.w);
    ((ushort4*)(out + (size_t)row * 1024))[t] = ov;
}

// ---------------------------------------------------------------------------
// GEMM: C[M,N] = A[M,K](bf16,rowmajor) * Bt[N,K](bf16,rowmajor)^T + bias
// mode 0: out bf16            mode 1: out fp32 + resid      mode 2: bf16 gelu
// 128x128x32 tile, 256 threads, 4 waves (2x2), global_load_lds staging.
// ---------------------------------------------------------------------------
__global__ __launch_bounds__(256) void gemm_bf16(
    const uint16_t* __restrict__ A, const uint16_t* __restrict__ Bt,
    int M, int N, int K,
    const float* __restrict__ bias, const float* __restrict__ resid,
    float* __restrict__ outF, uint16_t* __restrict__ outB, int mode)
{
    __shared__ __align__(16) uint16_t lA[128 * 32];
    __shared__ __align__(16) uint16_t lB[128 * 32];
    const int tid  = threadIdx.x;
    const int wave = tid >> 6, lane = tid & 63;
    const int m0 = blockIdx.y * 128, n0 = blockIdx.x * 128;
    const int wm = (wave >> 1) * 64, wn = (wave & 1) * 64;
    const int lrow = lane & 15, lk8 = (lane >> 4) * 8;
    const int wbase = wave * 64;

    floatx4 acc[4][4] = {};

    const uint16_t* aT = A  + (size_t)m0 * K;
    const uint16_t* bT = Bt + (size_t)n0 * K;

    for (int k0 = 0; k0 < K; k0 += 32) {
        __syncthreads();
#pragma unroll
        for (int i = 0; i < 2; ++i) {
            const int cw = i * 256 + wbase;      // wave-uniform chunk base
            const int c  = cw + lane;
            const int row = c >> 2, kc = (c & 3) * 8;
            gload_lds16(aT + (size_t)row * K + k0 + kc, &lA[cw * 8]);
            gload_lds16(bT + (size_t)row * K + k0 + kc, &lB[cw * 8]);
        }
        __syncthreads();
        bf16x8 af[4], bfr[4];
#pragma unroll
        for (int mi = 0; mi < 4; ++mi)
            af[mi] = *(const bf16x8*)&lA[(wm + mi * 16 + lrow) * 32 + lk8];
#pragma unroll
        for (int ni = 0; ni < 4; ++ni)
            bfr[ni] = *(const bf16x8*)&lB[(wn + ni * 16 + lrow) * 32 + lk8];
#pragma unroll
        for (int mi = 0; mi < 4; ++mi)
#pragma unroll
            for (int ni = 0; ni < 4; ++ni)
                acc[mi][ni] = __builtin_amdgcn_mfma_f32_16x16x32_bf16(
                    af[mi], bfr[ni], acc[mi][ni], 0, 0, 0);
    }

    const int r0 = (lane >> 4) * 4;
#pragma unroll
    for (int ni = 0; ni < 4; ++ni) {
        const int col = n0 + wn + ni * 16 + lrow;
        const float bv = bias[col];
#pragma unroll
        for (int mi = 0; mi < 4; ++mi) {
#pragma unroll
            for (int r = 0; r < 4; ++r) {
                const int row = m0 + wm + mi * 16 + r0 + r;
                const size_t idx = (size_t)row * N + col;
                float v = acc[mi][ni][r] + bv;
                if (mode == 1) {
                    outF[idx] = v + resid[idx];
                } else if (mode == 2) {
                    outB[idx] = f2b(0.5f * v * (1.0f + erff(v * 0.70710678118654752f)));
                } else {
                    outB[idx] = f2b(v);
                }
            }
        }
    }
}

// ---------------------------------------------------------------------------
// Flash attention (causal). Grid: (qtile=32, H=16, B=4). 256 thr = 4 waves.
// Wave w handles 16 q-rows. qkv: [B*T][3072] (Q|K|V), Vt: [(b,h),hd][T].
// ctx out: [B*T][1024] bf16, heads concatenated.
// ---------------------------------------------------------------------------
__global__ __launch_bounds__(256) void attn_kernel(
    const uint16_t* __restrict__ qkv, const uint16_t* __restrict__ Vt,
    uint16_t* __restrict__ ctx)
{
    const int qt = blockIdx.x, h = blockIdx.y, b = blockIdx.z;
    const int tid = threadIdx.x, wave = tid >> 6, lane = tid & 63;
    const int lcol = lane & 15, lq8 = (lane >> 4) * 8, lr4 = (lane >> 4) * 4;
    const uint16_t* qbase = qkv + (size_t)b * 2048 * 3072;

    __shared__ __align__(16) uint16_t pshm[4][16 * 64];

    bf16x8 qf[2];
    {
        const int qrow = qt * 64 + wave * 16 + lcol;     // A-frag m = lane&15
        const uint16_t* qp = qbase + (size_t)qrow * 3072 + h * 64;
        qf[0] = *(const bf16x8*)(qp + lq8);
        qf[1] = *(const bf16x8*)(qp + 32 + lq8);
    }

    floatx4 o[4] = {};
    float m_i[4] = {-1e30f, -1e30f, -1e30f, -1e30f};
    float l_i[4] = {0.f, 0.f, 0.f, 0.f};

    const uint16_t* vtb = Vt + (size_t)(b * 16 + h) * 64 * 2048;

    for (int kt = 0; kt <= qt; ++kt) {
        const int kb = kt * 64;
        floatx4 sv[4];
#pragma unroll
        for (int nt = 0; nt < 4; ++nt) {
            const int key = kb + nt * 16 + lcol;         // B-frag n = lane&15
            const uint16_t* kp = qbase + (size_t)key * 3072 + 1024 + h * 64;
            bf16x8 kf0 = *(const bf16x8*)(kp + lq8);
            bf16x8 kf1 = *(const bf16x8*)(kp + 32 + lq8);
            floatx4 s = {0.f, 0.f, 0.f, 0.f};
            s = __builtin_amdgcn_mfma_f32_16x16x32_bf16(qf[0], kf0, s, 0, 0, 0);
            s = __builtin_amdgcn_mfma_f32_16x16x32_bf16(qf[1], kf1, s, 0, 0, 0);
            sv[nt] = s;
        }
        const bool diag = (kt == qt);
#pragma unroll
        for (int nt = 0; nt < 4; ++nt)
#pragma unroll
            for (int r = 0; r < 4; ++r) {
                float s = sv[nt][r] * 0.125f;            // 1/sqrt(64)
                if (diag) {
                    const int rrow = wave * 16 + lr4 + r;
                    const int rcol = nt * 16 + lcol;
                    if (rcol > rrow) s = -1e30f;
                }
                sv[nt][r] = s;
            }
        float alpha[4];
#pragma unroll
        for (int r = 0; r < 4; ++r) {
            float m = fmaxf(fmaxf(sv[0][r], sv[1][r]), fmaxf(sv[2][r], sv[3][r]));
#pragma unroll
            for (int off = 8; off > 0; off >>= 1) m = fmaxf(m, __shfl_xor(m, off));
            const float mnew = fmaxf(m_i[r], m);
            alpha[r] = __expf(m_i[r] - mnew);
            m_i[r] = mnew;
        }
#pragma unroll
        for (int nt = 0; nt < 4; ++nt)
#pragma unroll
            for (int r = 0; r < 4; ++r) {
                const float p = __expf(sv[nt][r] - m_i[r]);
                sv[nt][r] = p;
                pshm[wave][(lr4 + r) * 64 + nt * 16 + lcol] = f2b(p);
            }
#pragma unroll
        for (int r = 0; r < 4; ++r) {
            float l = sv[0][r] + sv[1][r] + sv[2][r] + sv[3][r];
#pragma unroll
            for (int off = 8; off > 0; off >>= 1) l += __shfl_xor(l, off);
            l_i[r] = l_i[r] * alpha[r] + l;
        }
#pragma unroll
        for (int ht = 0; ht < 4; ++ht)
#pragma unroll
            for (int r = 0; r < 4; ++r) o[ht][r] *= alpha[r];

        // P: C-layout -> A-layout via per-wave LDS round-trip
        const bf16x8 pf0 = *(const bf16x8*)&pshm[wave][lcol * 64 + lq8];
        const bf16x8 pf1 = *(const bf16x8*)&pshm[wave][lcol * 64 + 32 + lq8];
#pragma unroll
        for (int ht = 0; ht < 4; ++ht) {
            const uint16_t* vp = vtb + (size_t)(ht * 16 + lcol) * 2048 + kb;
            const bf16x8 vf0 = *(const bf16x8*)(vp + lq8);
            const bf16x8 vf1 = *(const bf16x8*)(vp + 32 + lq8);
            o[ht] = __builtin_amdgcn_mfma_f32_16x16x32_bf16(pf0, vf0, o[ht], 0, 0, 0);
            o[ht] = __builtin_amdgcn_mfma_f32_16x16x32_bf16(pf1, vf1, o[ht], 0, 0, 0);
        }
    }

#pragma unroll
    for (int ht = 0; ht < 4; ++ht)
#pragma unroll
        for (int r = 0; r < 4; ++r) {
            const int row = qt * 64 + wave * 16 + lr4 + r;
            const float ov = o[ht][r] / l_i[r];
            ctx[(size_t)(b * 2048 + row) * 1024 + h * 64 + ht * 16 + lcol] = f2b(ov);
        }
}

// ---------------------------------------------------------------------------
// Launch
// ---------------------------------------------------------------------------
extern "C" void kernel_launch(void* const* d_in, const int* in_sizes, int n_in,
                              void* d_out, int out_size, void* d_ws, size_t ws_size,
                              hipStream_t stream)
{
    (void)in_sizes; (void)n_in; (void)out_size; (void)ws_size;
    const float* x     = (const float*)d_in[0];
    // d_in[1] = mask (causal tril) — hardcoded in attn kernel
    const float* ln1_g = (const float*)d_in[2];
    const float* ln1_b = (const float*)d_in[3];
    const float* Wq    = (const float*)d_in[4];
    const float* bq    = (const float*)d_in[5];
    const float* Wk    = (const float*)d_in[6];
    const float* bk    = (const float*)d_in[7];
    const float* Wv    = (const float*)d_in[8];
    const float* bv    = (const float*)d_in[9];
    const float* Wo    = (const float*)d_in[10];
    const float* bo    = (const float*)d_in[11];
    const float* ln2_g = (const float*)d_in[12];
    const float* ln2_b = (const float*)d_in[13];
    const float* W1    = (const float*)d_in[14];
    const float* b1    = (const float*)d_in[15];
    const float* W2    = (const float*)d_in[16];
    const float* b2    = (const float*)d_in[17];
    float* out = (float*)d_out;

    // workspace carve (total ~142.6 MB)
    char* w = (char*)d_ws;
    uint16_t* Wqkv_t = (uint16_t*)w;  w += 6291456;    // [3072][1024]
    uint16_t* Wo_t   = (uint16_t*)w;  w += 2097152;    // [1024][1024]
    uint16_t* W1_t   = (uint16_t*)w;  w += 8388608;    // [4096][1024]
    uint16_t* W2_t   = (uint16_t*)w;  w += 8388608;    // [1024][4096]
    float*    bqkv   = (float*)w;     w += 16384;      // [3072]
    float*    x2     = (float*)w;     w += 33554432;   // [8192][1024] fp32
    char* region = w;                                  // 83886080 bytes, reused
    uint16_t* hbuf = (uint16_t*)region;                        // 16MB h, later ctx
    uint16_t* qkv  = (uint16_t*)(region + 16777216);           // 48MB
    uint16_t* Vt   = (uint16_t*)(region + 16777216 + 50331648);// 16MB
    uint16_t* ctx  = hbuf;
    uint16_t* h2   = (uint16_t*)region;                        // alias (h/ctx dead)
    uint16_t* a1   = (uint16_t*)(region + 16777216);           // alias qkv+Vt (dead)

    // 1. weight repack (bf16, transposed)
    repack_qkv<<<dim3(32, 2, 48), 256, 0, stream>>>(Wq, Wk, Wv, Wqkv_t);
    transpose_f2b<<<dim3(32, 32),  256, 0, stream>>>(Wo, Wo_t, 1024, 1024);
    transpose_f2b<<<dim3(128, 32), 256, 0, stream>>>(W1, W1_t, 1024, 4096);
    transpose_f2b<<<dim3(32, 128), 256, 0, stream>>>(W2, W2_t, 4096, 1024);
    concat_bias<<<12, 256, 0, stream>>>(bq, bk, bv, bqkv);
    // 2. LN1: x -> h (bf16)
    ln_bf16<<<8192, 256, 0, stream>>>(x, ln1_g, ln1_b, hbuf);
    // 3. QKV projection: h @ Wqkv^T -> qkv [8192][3072]
    gemm_bf16<<<dim3(24, 64), 256, 0, stream>>>(hbuf, Wqkv_t, 8192, 3072, 1024,
                                                bqkv, nullptr, nullptr, qkv, 0);
    // 4. V transpose for PV fragment loads
    transpose_v<<<dim3(64, 2, 64), 256, 0, stream>>>(qkv, Vt);
    // 5. causal flash attention -> ctx (bf16)
    attn_kernel<<<dim3(32, 16, 4), 256, 0, stream>>>(qkv, Vt, ctx);
    // 6. output projection + residual: ctx @ Wo^T + bo + x -> x2 (fp32)
    gemm_bf16<<<dim3(8, 64), 256, 0, stream>>>(ctx, Wo_t, 8192, 1024, 1024,
                                               bo, x, x2, nullptr, 1);
    // 7. LN2: x2 -> h2 (bf16)
    ln_bf16<<<8192, 256, 0, stream>>>(x2, ln2_g, ln2_b, h2);
    // 8. FFN1 + exact GELU: h2 @ W1^T + b1 -> a1 (bf16)
    gemm_bf16<<<dim3(32, 64), 256, 0, stream>>>(h2, W1_t, 8192, 4096, 1024,
                                                b1, nullptr, nullptr, a1, 2);
    // 9. FFN2 + residual: a1 @ W2^T + b2 + x2 -> out (fp32)
    gemm_bf16<<<dim3(8, 64), 256, 0, stream>>>(a1, W2_t, 8192, 1024, 4096,
                                               b2, x2, out, nullptr, 1);
}

// Round 2
// 800.025 us; speedup vs baseline: 1.2543x; 1.2543x over previous
//
#include <hip/hip_runtime.h>
#include <cstdint>
#include <cstddef>

// ---------------------------------------------------------------------------
// Types / helpers
// ---------------------------------------------------------------------------
typedef __bf16 bf16x8 __attribute__((ext_vector_type(8)));
typedef float  floatx4 __attribute__((ext_vector_type(4)));

__device__ __forceinline__ uint16_t f2b(float f) {
    uint32_t u = __builtin_bit_cast(uint32_t, f);
    return (uint16_t)((u + 0x7fffu + ((u >> 16) & 1)) >> 16);  // RNE
}

__device__ __forceinline__ void gload_lds16(const void* g, void* l) {
    // async 16B/lane global->LDS; LDS dest = wave-uniform base + lane*16
    __builtin_amdgcn_global_load_lds(
        (__attribute__((address_space(1))) void*)(void*)g,
        (__attribute__((address_space(3))) void*)l, 16, 0, 0);
}

// ---------------------------------------------------------------------------
// Weight repack kernels (fp32 -> bf16, transposed to [N][K])
// ---------------------------------------------------------------------------
__global__ __launch_bounds__(256) void repack_qkv(
    const float* __restrict__ Wq, const float* __restrict__ Wk,
    const float* __restrict__ Wv, uint16_t* __restrict__ out)
{
    __shared__ uint16_t tile[32][33];
    const int m = blockIdx.z >> 4, h = blockIdx.z & 15;
    const float* W = (m == 0) ? Wq : (m == 1) ? Wk : Wv;
    const float* src = W + (size_t)h * 1024 * 64;           // [1024][64]
    const int d0 = blockIdx.x * 32, hd0 = blockIdx.y * 32;
    const int tx = threadIdx.x & 31, ty = threadIdx.x >> 5;
#pragma unroll
    for (int i = 0; i < 4; ++i)
        tile[ty + i * 8][tx] = f2b(src[(size_t)(d0 + ty + i * 8) * 64 + hd0 + tx]);
    __syncthreads();
    uint16_t* dst = out + (size_t)(m * 1024 + h * 64) * 1024; // [64][1024]
#pragma unroll
    for (int i = 0; i < 4; ++i)
        dst[(size_t)(hd0 + ty + i * 8) * 1024 + d0 + tx] = tile[tx][ty + i * 8];
}

__global__ __launch_bounds__(256) void transpose_f2b(
    const float* __restrict__ in, uint16_t* __restrict__ out, int R, int C)
{
    __shared__ uint16_t tile[32][33];
    const int c0 = blockIdx.x * 32, r0 = blockIdx.y * 32;
    const int tx = threadIdx.x & 31, ty = threadIdx.x >> 5;
#pragma unroll
    for (int i = 0; i < 4; ++i)
        tile[ty + i * 8][tx] = f2b(in[(size_t)(r0 + ty + i * 8) * C + c0 + tx]);
    __syncthreads();
#pragma unroll
    for (int i = 0; i < 4; ++i)
        out[(size_t)(c0 + ty + i * 8) * R + r0 + tx] = tile[tx][ty + i * 8];
}

__global__ void concat_bias(const float* __restrict__ bq, const float* __restrict__ bk,
                            const float* __restrict__ bv, float* __restrict__ out)
{
    int i = blockIdx.x * 256 + threadIdx.x;  // 3072 total
    out[i] = (i < 1024) ? bq[i] : (i < 2048) ? bk[i - 1024] : bv[i - 2048];
}

// V slice of qkv [B*T][3072] (cols 2048+h*64+hd) -> Vt [(b*16+h)*64+hd][2048]
__global__ __launch_bounds__(256) void transpose_v(
    const uint16_t* __restrict__ qkv, uint16_t* __restrict__ Vt)
{
    __shared__ uint16_t tile[32][33];
    const int bh = blockIdx.z;
    const int b = bh >> 4, h = bh & 15;
    const int t0 = blockIdx.x * 32, hd0 = blockIdx.y * 32;
    const int tx = threadIdx.x & 31, ty = threadIdx.x >> 5;
    const uint16_t* src = qkv + (size_t)b * 2048 * 3072 + 2048 + h * 64;
#pragma unroll
    for (int i = 0; i < 4; ++i)
        tile[ty + i * 8][tx] = src[(size_t)(t0 + ty + i * 8) * 3072 + hd0 + tx];
    __syncthreads();
    uint16_t* dst = Vt + (size_t)bh * 64 * 2048;
#pragma unroll
    for (int i = 0; i < 4; ++i)
        dst[(size_t)(hd0 + ty + i * 8) * 2048 + t0 + tx] = tile[tx][ty + i * 8];
}

// ---------------------------------------------------------------------------
// LayerNorm: fp32 [rows][1024] -> bf16, one block per row
// ---------------------------------------------------------------------------
__global__ __launch_bounds__(256) void ln_bf16(
    const float* __restrict__ x, const float* __restrict__ g,
    const float* __restrict__ b, uint16_t* __restrict__ out)
{
    const int row = blockIdx.x;
    const int t = threadIdx.x;
    const float4 v = ((const float4*)(x + (size_t)row * 1024))[t];
    float s  = v.x + v.y + v.z + v.w;
    float s2 = v.x * v.x + v.y * v.y + v.z * v.z + v.w * v.w;
#pragma unroll
    for (int o = 32; o > 0; o >>= 1) { s += __shfl_down(s, o); s2 += __shfl_down(s2, o); }
    __shared__ float red[8];
    const int wave = t >> 6, lane = t & 63;
    if (lane == 0) { red[wave] = s; red[4 + wave] = s2; }
    __syncthreads();
    if (t == 0) {
        float a  = red[0] + red[1] + red[2] + red[3];
        float a2 = red[4] + red[5] + red[6] + red[7];
        float mu = a * (1.0f / 1024.0f);
        red[0] = mu;
        red[4] = rsqrtf(a2 * (1.0f / 1024.0f) - mu * mu + 1e-5f);
    }
    __syncthreads();
    const float mu = red[0], rs = red[4];
    const float4 gv = ((const float4*)g)[t];
    const float4 bv = ((const float4*)b)[t];
    ushort4 ov;
    ov.x = f2b((v.x - mu) * rs * gv.x + bv.x);
    ov.y = f2b((v.y - mu) * rs * gv.y + bv.y);
    ov.z = f2b((v.z - mu) * rs * gv.z + bv.z);
    ov.w = f2b((v.w - mu) * rs * gv.w + bv.w);
    ((ushort4*)(out + (size_t)row * 1024))[t] = ov;
}

// ---------------------------------------------------------------------------
// GEMM: C[M,N] = A[M,K](bf16,rowmajor) * Bt[N,K](bf16,rowmajor)^T + bias
// mode 0: out bf16            mode 1: out fp32 + resid      mode 2: bf16 gelu
// ---------------------------------------------------------------------------
__global__ __launch_bounds__(256) void gemm_bf16(
    const uint16_t* __restrict__ A, const uint16_t* __restrict__ Bt,
    int M, int N, int K,
    const float* __restrict__ bias, const float* __restrict__ resid,
    float* __restrict__ outF, uint16_t* __restrict__ outB, int mode)
{
    __shared__ __align__(16) uint16_t lA[128 * 32];
    __shared__ __align__(16) uint16_t lB[128 * 32];
    const int tid  = threadIdx.x;
    const int wave = tid >> 6, lane = tid & 63;
    const int m0 = blockIdx.y * 128, n0 = blockIdx.x * 128;
    const int wm = (wave >> 1) * 64, wn = (wave & 1) * 64;
    const int lrow = lane & 15, lk8 = (lane >> 4) * 8;
    const int wbase = wave * 64;

    floatx4 acc[4][4] = {};

    const uint16_t* aT = A  + (size_t)m0 * K;
    const uint16_t* bT = Bt + (size_t)n0 * K;

    for (int k0 = 0; k0 < K; k0 += 32) {
        __syncthreads();
#pragma unroll
        for (int i = 0; i < 2; ++i) {
            const int cw = i * 256 + wbase;      // wave-uniform chunk base
            const int c  = cw + lane;
            const int row = c >> 2, kc = (c & 3) * 8;
            gload_lds16(aT + (size_t)row * K + k0 + kc, &lA[cw * 8]);
            gload_lds16(bT + (size_t)row * K + k0 + kc, &lB[cw * 8]);
        }
        __syncthreads();
        bf16x8 af[4], bfr[4];
#pragma unroll
        for (int mi = 0; mi < 4; ++mi)
            af[mi] = *(const bf16x8*)&lA[(wm + mi * 16 + lrow) * 32 + lk8];
#pragma unroll
        for (int ni = 0; ni < 4; ++ni)
            bfr[ni] = *(const bf16x8*)&lB[(wn + ni * 16 + lrow) * 32 + lk8];
#pragma unroll
        for (int mi = 0; mi < 4; ++mi)
#pragma unroll
            for (int ni = 0; ni < 4; ++ni)
                acc[mi][ni] = __builtin_amdgcn_mfma_f32_16x16x32_bf16(
                    af[mi], bfr[ni], acc[mi][ni], 0, 0, 0);
    }

    const int r0 = (lane >> 4) * 4;
#pragma unroll
    for (int ni = 0; ni < 4; ++ni) {
        const int col = n0 + wn + ni * 16 + lrow;
        const float bv = bias[col];
#pragma unroll
        for (int mi = 0; mi < 4; ++mi) {
#pragma unroll
            for (int r = 0; r < 4; ++r) {
                const int row = m0 + wm + mi * 16 + r0 + r;
                const size_t idx = (size_t)row * N + col;
                float v = acc[mi][ni][r] + bv;
                if (mode == 1) {
                    outF[idx] = v + resid[idx];
                } else if (mode == 2) {
                    outB[idx] = f2b(0.5f * v * (1.0f + erff(v * 0.70710678118654752f)));
                } else {
                    outB[idx] = f2b(v);
                }
            }
        }
    }
}

// ---------------------------------------------------------------------------
// Flash attention v2 (causal). Grid: (16, H=16, B=4); qt reversed so heavy
// blocks dispatch first. 256 thr = 4 waves; wave w owns q rows [w*32, w*32+32).
// K/V 64x64 tiles cooperatively staged to LDS via global_load_lds, double-
// buffered, 16B chunks XOR-swizzled (slot = chunk ^ (row&7)) for conflict-free
// b128 fragment reads. Softmax in exp2 domain. P->A-layout via swizzled pshm.
// ---------------------------------------------------------------------------
__global__ __launch_bounds__(256) void attn_kernel(
    const uint16_t* __restrict__ qkv, const uint16_t* __restrict__ Vt,
    uint16_t* __restrict__ ctx)
{
    const int qt = (int)gridDim.x - 1 - (int)blockIdx.x;
    const int h = blockIdx.y, b = blockIdx.z;
    const int tid = threadIdx.x, wave = tid >> 6, lane = tid & 63;
    const int quad = lane >> 4, lcol = lane & 15, lr4 = quad * 4;
    const int sx = lcol & 7;
    const uint16_t* qbase = qkv + (size_t)b * 2048 * 3072;
    const uint16_t* kgb = qbase + 1024 + h * 64;
    const uint16_t* vtb = Vt + (size_t)(b * 16 + h) * 64 * 2048;

    __shared__ __align__(16) uint16_t kbuf[2][64 * 64];
    __shared__ __align__(16) uint16_t vbuf[2][64 * 64];
    __shared__ __align__(16) uint16_t pshm[4][32 * 64];

    const int qr0 = qt * 128 + wave * 32;

    // Q fragments (A-layout): m = lcol, k = quad*8+j (+32 for second chunk)
    bf16x8 qf[2][2];
#pragma unroll
    for (int mi = 0; mi < 2; ++mi) {
        const uint16_t* qp = qbase + (size_t)(qr0 + mi * 16 + lcol) * 3072 + h * 64;
        qf[mi][0] = *(const bf16x8*)(qp + quad * 8);
        qf[mi][1] = *(const bf16x8*)(qp + 32 + quad * 8);
    }

    floatx4 o[2][4] = {};
    float m_i[2][4], l_i[2][4];
#pragma unroll
    for (int mi = 0; mi < 2; ++mi)
#pragma unroll
        for (int r = 0; r < 4; ++r) { m_i[mi][r] = -1e30f; l_i[mi][r] = 0.f; }

    const int nk = 2 * qt + 2;
    const int rr = lane >> 3, sl = lane & 7;
    const int swz = sl ^ rr;                 // global 16B-chunk this lane fetches

    const float sc = 0.125f * 1.44269504088896f;  // 1/sqrt(64) * log2(e)

#define STAGE(ktile, bb)                                                        \
    {                                                                           \
        const int _kb = (ktile) * 64;                                           \
        _Pragma("unroll")                                                       \
        for (int i = 0; i < 2; ++i) {                                           \
            const int j = wave * 2 + i;                                         \
            const int r = j * 8 + rr;                                           \
            gload_lds16(kgb + (size_t)(_kb + r) * 3072 + swz * 8,               \
                        &kbuf[bb][j * 512]);                                    \
            gload_lds16(vtb + (size_t)r * 2048 + _kb + swz * 8,                 \
                        &vbuf[bb][j * 512]);                                    \
        }                                                                       \
    }

    STAGE(0, 0);
    int cur = 0;

    for (int kt = 0; kt < nk; ++kt) {
        const int kb = kt * 64;
        __syncthreads();                       // drains vmcnt: buf[cur] ready
        if (kt + 1 < nk) STAGE(kt + 1, cur ^ 1);

        if (kb <= qr0 + 31) {                  // wave-uniform causal skip
            // ---- QK^T ----
            bf16x8 kf[4][2];
#pragma unroll
            for (int nt = 0; nt < 4; ++nt) {
                const int krow = nt * 16 + lcol;
                kf[nt][0] = *(const bf16x8*)&kbuf[cur][krow * 64 + ((quad ^ sx) * 8)];
                kf[nt][1] = *(const bf16x8*)&kbuf[cur][krow * 64 + (((quad + 4) ^ sx) * 8)];
            }
            floatx4 sv[2][4];
#pragma unroll
            for (int mi = 0; mi < 2; ++mi)
#pragma unroll
                for (int nt = 0; nt < 4; ++nt) {
                    floatx4 s = {0.f, 0.f, 0.f, 0.f};
                    s = __builtin_amdgcn_mfma_f32_16x16x32_bf16(qf[mi][0], kf[nt][0], s, 0, 0, 0);
                    s = __builtin_amdgcn_mfma_f32_16x16x32_bf16(qf[mi][1], kf[nt][1], s, 0, 0, 0);
                    sv[mi][nt] = s;
                }
            // ---- scale + causal mask (exp2 domain) ----
            const bool diag = (kb + 63 > qr0);
#pragma unroll
            for (int mi = 0; mi < 2; ++mi)
#pragma unroll
                for (int nt = 0; nt < 4; ++nt)
#pragma unroll
                    for (int r = 0; r < 4; ++r) {
                        float s = sv[mi][nt][r] * sc;
                        if (diag) {
                            const int row = qr0 + mi * 16 + lr4 + r;
                            const int col = kb + nt * 16 + lcol;
                            if (col > row) s = -1e30f;
                        }
                        sv[mi][nt][r] = s;
                    }
            // ---- online softmax ----
            float alpha[2][4];
#pragma unroll
            for (int mi = 0; mi < 2; ++mi)
#pragma unroll
                for (int r = 0; r < 4; ++r) {
                    float m = fmaxf(fmaxf(sv[mi][0][r], sv[mi][1][r]),
                                    fmaxf(sv[mi][2][r], sv[mi][3][r]));
#pragma unroll
                    for (int off = 8; off > 0; off >>= 1) m = fmaxf(m, __shfl_xor(m, off));
                    const float mn = fmaxf(m_i[mi][r], m);
                    alpha[mi][r] = __builtin_amdgcn_exp2f(m_i[mi][r] - mn);
                    m_i[mi][r] = mn;
                }
#pragma unroll
            for (int mi = 0; mi < 2; ++mi)
#pragma unroll
                for (int r = 0; r < 4; ++r) {
                    const int row = mi * 16 + lr4 + r;
                    const int rsw = row & 7;
                    float l = 0.f;
#pragma unroll
                    for (int nt = 0; nt < 4; ++nt) {
                        const float p = __builtin_amdgcn_exp2f(sv[mi][nt][r] - m_i[mi][r]);
                        l += p;
                        const int col = nt * 16 + lcol;
                        pshm[wave][row * 64 + (((col >> 3) ^ rsw) * 8) + (col & 7)] = f2b(p);
                    }
#pragma unroll
                    for (int off = 8; off > 0; off >>= 1) l += __shfl_xor(l, off);
                    l_i[mi][r] = l_i[mi][r] * alpha[mi][r] + l;
#pragma unroll
                    for (int ht = 0; ht < 4; ++ht) o[mi][ht][r] *= alpha[mi][r];
                }
            // ---- P (A-layout) from pshm, V (B-layout) from vbuf, PV MFMA ----
            bf16x8 pf[2][2];
#pragma unroll
            for (int mi = 0; mi < 2; ++mi) {
                const int prow = mi * 16 + lcol;
                pf[mi][0] = *(const bf16x8*)&pshm[wave][prow * 64 + ((quad ^ sx) * 8)];
                pf[mi][1] = *(const bf16x8*)&pshm[wave][prow * 64 + (((quad + 4) ^ sx) * 8)];
            }
#pragma unroll
            for (int ht = 0; ht < 4; ++ht) {
                const int hd = ht * 16 + lcol;
                const bf16x8 vf0 = *(const bf16x8*)&vbuf[cur][hd * 64 + ((quad ^ sx) * 8)];
                const bf16x8 vf1 = *(const bf16x8*)&vbuf[cur][hd * 64 + (((quad + 4) ^ sx) * 8)];
#pragma unroll
                for (int mi = 0; mi < 2; ++mi) {
                    o[mi][ht] = __builtin_amdgcn_mfma_f32_16x16x32_bf16(pf[mi][0], vf0, o[mi][ht], 0, 0, 0);
                    o[mi][ht] = __builtin_amdgcn_mfma_f32_16x16x32_bf16(pf[mi][1], vf1, o[mi][ht], 0, 0, 0);
                }
            }
        }
        cur ^= 1;
    }
#undef STAGE

#pragma unroll
    for (int mi = 0; mi < 2; ++mi)
#pragma unroll
        for (int ht = 0; ht < 4; ++ht)
#pragma unroll
            for (int r = 0; r < 4; ++r) {
                const int row = qr0 + mi * 16 + lr4 + r;
                ctx[(size_t)(b * 2048 + row) * 1024 + h * 64 + ht * 16 + lcol] =
                    f2b(o[mi][ht][r] / l_i[mi][r]);
            }
}

// ---------------------------------------------------------------------------
// Launch
// ---------------------------------------------------------------------------
extern "C" void kernel_launch(void* const* d_in, const int* in_sizes, int n_in,
                              void* d_out, int out_size, void* d_ws, size_t ws_size,
                              hipStream_t stream)
{
    (void)in_sizes; (void)n_in; (void)out_size; (void)ws_size;
    const float* x     = (const float*)d_in[0];
    const float* ln1_g = (const float*)d_in[2];
    const float* ln1_b = (const float*)d_in[3];
    const float* Wq    = (const float*)d_in[4];
    const float* bq    = (const float*)d_in[5];
    const float* Wk    = (const float*)d_in[6];
    const float* bk    = (const float*)d_in[7];
    const float* Wv    = (const float*)d_in[8];
    const float* bv    = (const float*)d_in[9];
    const float* Wo    = (const float*)d_in[10];
    const float* bo    = (const float*)d_in[11];
    const float* ln2_g = (const float*)d_in[12];
    const float* ln2_b = (const float*)d_in[13];
    const float* W1    = (const float*)d_in[14];
    const float* b1    = (const float*)d_in[15];
    const float* W2    = (const float*)d_in[16];
    const float* b2    = (const float*)d_in[17];
    float* out = (float*)d_out;

    char* w = (char*)d_ws;
    uint16_t* Wqkv_t = (uint16_t*)w;  w += 6291456;    // [3072][1024]
    uint16_t* Wo_t   = (uint16_t*)w;  w += 2097152;    // [1024][1024]
    uint16_t* W1_t   = (uint16_t*)w;  w += 8388608;    // [4096][1024]
    uint16_t* W2_t   = (uint16_t*)w;  w += 8388608;    // [1024][4096]
    float*    bqkv   = (float*)w;     w += 16384;      // [3072]
    float*    x2     = (float*)w;     w += 33554432;   // [8192][1024] fp32
    char* region = w;
    uint16_t* hbuf = (uint16_t*)region;                        // 16MB h, later ctx
    uint16_t* qkv  = (uint16_t*)(region + 16777216);           // 48MB
    uint16_t* Vt   = (uint16_t*)(region + 16777216 + 50331648);// 16MB
    uint16_t* ctx  = hbuf;
    uint16_t* h2   = (uint16_t*)region;
    uint16_t* a1   = (uint16_t*)(region + 16777216);

    repack_qkv<<<dim3(32, 2, 48), 256, 0, stream>>>(Wq, Wk, Wv, Wqkv_t);
    transpose_f2b<<<dim3(32, 32),  256, 0, stream>>>(Wo, Wo_t, 1024, 1024);
    transpose_f2b<<<dim3(128, 32), 256, 0, stream>>>(W1, W1_t, 1024, 4096);
    transpose_f2b<<<dim3(32, 128), 256, 0, stream>>>(W2, W2_t, 4096, 1024);
    concat_bias<<<12, 256, 0, stream>>>(bq, bk, bv, bqkv);
    ln_bf16<<<8192, 256, 0, stream>>>(x, ln1_g, ln1_b, hbuf);
    gemm_bf16<<<dim3(24, 64), 256, 0, stream>>>(hbuf, Wqkv_t, 8192, 3072, 1024,
                                                bqkv, nullptr, nullptr, qkv, 0);
    transpose_v<<<dim3(64, 2, 64), 256, 0, stream>>>(qkv, Vt);
    attn_kernel<<<dim3(16, 16, 4), 256, 0, stream>>>(qkv, Vt, ctx);
    gemm_bf16<<<dim3(8, 64), 256, 0, stream>>>(ctx, Wo_t, 8192, 1024, 1024,
                                               bo, x, x2, nullptr, 1);
    ln_bf16<<<8192, 256, 0, stream>>>(x2, ln2_g, ln2_b, h2);
    gemm_bf16<<<dim3(32, 64), 256, 0, stream>>>(h2, W1_t, 8192, 4096, 1024,
                                                b1, nullptr, nullptr, a1, 2);
    gemm_bf16<<<dim3(8, 64), 256, 0, stream>>>(a1, W2_t, 8192, 1024, 4096,
                                               b2, x2, out, nullptr, 1);
}

// Round 3
// 700.180 us; speedup vs baseline: 1.4331x; 1.1426x over previous
//
#include <hip/hip_runtime.h>
#include <cstdint>
#include <cstddef>

// ---------------------------------------------------------------------------
// Types / helpers
// ---------------------------------------------------------------------------
typedef __bf16 bf16x8 __attribute__((ext_vector_type(8)));
typedef float  floatx4 __attribute__((ext_vector_type(4)));

__device__ __forceinline__ uint16_t f2b(float f) {
    uint32_t u = __builtin_bit_cast(uint32_t, f);
    return (uint16_t)((u + 0x7fffu + ((u >> 16) & 1)) >> 16);  // RNE
}

__device__ __forceinline__ uint16_t bf16bits(float f) {       // HW v_cvt (RNE)
    __bf16 h = (__bf16)f;
    return __builtin_bit_cast(uint16_t, h);
}

__device__ __forceinline__ void gload_lds16(const void* g, void* l) {
    __builtin_amdgcn_global_load_lds(
        (__attribute__((address_space(1))) void*)(void*)g,
        (__attribute__((address_space(3))) void*)l, 16, 0, 0);
}

// DPP row_ror helpers: 16-lane-row reductions entirely in the VALU pipe.
template<int CTRL>
__device__ __forceinline__ float dpp_rot(float v) {
    return __builtin_bit_cast(float,
        __builtin_amdgcn_update_dpp(0, __builtin_bit_cast(int, v),
                                    CTRL, 0xf, 0xf, true));
}
__device__ __forceinline__ float rowmax16(float v) {
    v = fmaxf(v, dpp_rot<0x128>(v));   // ror 8
    v = fmaxf(v, dpp_rot<0x124>(v));   // ror 4
    v = fmaxf(v, dpp_rot<0x122>(v));   // ror 2
    v = fmaxf(v, dpp_rot<0x121>(v));   // ror 1
    return v;
}
__device__ __forceinline__ float rowsum16(float v) {
    v += dpp_rot<0x128>(v);
    v += dpp_rot<0x124>(v);
    v += dpp_rot<0x122>(v);
    v += dpp_rot<0x121>(v);
    return v;
}

// 0.125 (1/sqrt(HD)) * log2(e): folded into Wq/bq so softmax is exp2-domain.
#define QSCALE 0.18033688011112042f

// ---------------------------------------------------------------------------
// Weight repack kernels (fp32 -> bf16, transposed to [N][K])
// ---------------------------------------------------------------------------
__global__ __launch_bounds__(256) void repack_qkv(
    const float* __restrict__ Wq, const float* __restrict__ Wk,
    const float* __restrict__ Wv, uint16_t* __restrict__ out)
{
    __shared__ uint16_t tile[32][33];
    const int m = blockIdx.z >> 4, h = blockIdx.z & 15;
    const float* W = (m == 0) ? Wq : (m == 1) ? Wk : Wv;
    const float scl = (m == 0) ? QSCALE : 1.0f;
    const float* src = W + (size_t)h * 1024 * 64;           // [1024][64]
    const int d0 = blockIdx.x * 32, hd0 = blockIdx.y * 32;
    const int tx = threadIdx.x & 31, ty = threadIdx.x >> 5;
#pragma unroll
    for (int i = 0; i < 4; ++i)
        tile[ty + i * 8][tx] = f2b(src[(size_t)(d0 + ty + i * 8) * 64 + hd0 + tx] * scl);
    __syncthreads();
    uint16_t* dst = out + (size_t)(m * 1024 + h * 64) * 1024; // [64][1024]
#pragma unroll
    for (int i = 0; i < 4; ++i)
        dst[(size_t)(hd0 + ty + i * 8) * 1024 + d0 + tx] = tile[tx][ty + i * 8];
}

__global__ __launch_bounds__(256) void transpose_f2b(
    const float* __restrict__ in, uint16_t* __restrict__ out, int R, int C)
{
    __shared__ uint16_t tile[32][33];
    const int c0 = blockIdx.x * 32, r0 = blockIdx.y * 32;
    const int tx = threadIdx.x & 31, ty = threadIdx.x >> 5;
#pragma unroll
    for (int i = 0; i < 4; ++i)
        tile[ty + i * 8][tx] = f2b(in[(size_t)(r0 + ty + i * 8) * C + c0 + tx]);
    __syncthreads();
#pragma unroll
    for (int i = 0; i < 4; ++i)
        out[(size_t)(c0 + ty + i * 8) * R + r0 + tx] = tile[tx][ty + i * 8];
}

__global__ void concat_bias(const float* __restrict__ bq, const float* __restrict__ bk,
                            const float* __restrict__ bv, float* __restrict__ out)
{
    int i = blockIdx.x * 256 + threadIdx.x;  // 3072 total
    out[i] = (i < 1024) ? bq[i] * QSCALE : (i < 2048) ? bk[i - 1024] : bv[i - 2048];
}

// V slice of qkv [B*T][3072] (cols 2048+h*64+hd) -> Vt [(b*16+h)*64+hd][2048]
__global__ __launch_bounds__(256) void transpose_v(
    const uint16_t* __restrict__ qkv, uint16_t* __restrict__ Vt)
{
    __shared__ uint16_t tile[32][33];
    const int bh = blockIdx.z;
    const int b = bh >> 4, h = bh & 15;
    const int t0 = blockIdx.x * 32, hd0 = blockIdx.y * 32;
    const int tx = threadIdx.x & 31, ty = threadIdx.x >> 5;
    const uint16_t* src = qkv + (size_t)b * 2048 * 3072 + 2048 + h * 64;
#pragma unroll
    for (int i = 0; i < 4; ++i)
        tile[ty + i * 8][tx] = src[(size_t)(t0 + ty + i * 8) * 3072 + hd0 + tx];
    __syncthreads();
    uint16_t* dst = Vt + (size_t)bh * 64 * 2048;
#pragma unroll
    for (int i = 0; i < 4; ++i)
        dst[(size_t)(hd0 + ty + i * 8) * 2048 + t0 + tx] = tile[tx][ty + i * 8];
}

// ---------------------------------------------------------------------------
// LayerNorm: fp32 [rows][1024] -> bf16, one block per row
// ---------------------------------------------------------------------------
__global__ __launch_bounds__(256) void ln_bf16(
    const float* __restrict__ x, const float* __restrict__ g,
    const float* __restrict__ b, uint16_t* __restrict__ out)
{
    const int row = blockIdx.x;
    const int t = threadIdx.x;
    const float4 v = ((const float4*)(x + (size_t)row * 1024))[t];
    float s  = v.x + v.y + v.z + v.w;
    float s2 = v.x * v.x + v.y * v.y + v.z * v.z + v.w * v.w;
#pragma unroll
    for (int o = 32; o > 0; o >>= 1) { s += __shfl_down(s, o); s2 += __shfl_down(s2, o); }
    __shared__ float red[8];
    const int wave = t >> 6, lane = t & 63;
    if (lane == 0) { red[wave] = s; red[4 + wave] = s2; }
    __syncthreads();
    if (t == 0) {
        float a  = red[0] + red[1] + red[2] + red[3];
        float a2 = red[4] + red[5] + red[6] + red[7];
        float mu = a * (1.0f / 1024.0f);
        red[0] = mu;
        red[4] = rsqrtf(a2 * (1.0f / 1024.0f) - mu * mu + 1e-5f);
    }
    __syncthreads();
    const float mu = red[0], rs = red[4];
    const float4 gv = ((const float4*)g)[t];
    const float4 bv = ((const float4*)b)[t];
    ushort4 ov;
    ov.x = f2b((v.x - mu) * rs * gv.x + bv.x);
    ov.y = f2b((v.y - mu) * rs * gv.y + bv.y);
    ov.z = f2b((v.z - mu) * rs * gv.z + bv.z);
    ov.w = f2b((v.w - mu) * rs * gv.w + bv.w);
    ((ushort4*)(out + (size_t)row * 1024))[t] = ov;
}

// ---------------------------------------------------------------------------
// GEMM: C[M,N] = A[M,K](bf16,rowmajor) * Bt[N,K](bf16,rowmajor)^T + bias
// mode 0: out bf16            mode 1: out fp32 + resid      mode 2: bf16 gelu
// ---------------------------------------------------------------------------
__global__ __launch_bounds__(256) void gemm_bf16(
    const uint16_t* __restrict__ A, const uint16_t* __restrict__ Bt,
    int M, int N, int K,
    const float* __restrict__ bias, const float* __restrict__ resid,
    float* __restrict__ outF, uint16_t* __restrict__ outB, int mode)
{
    __shared__ __align__(16) uint16_t lA[128 * 32];
    __shared__ __align__(16) uint16_t lB[128 * 32];
    const int tid  = threadIdx.x;
    const int wave = tid >> 6, lane = tid & 63;
    const int m0 = blockIdx.y * 128, n0 = blockIdx.x * 128;
    const int wm = (wave >> 1) * 64, wn = (wave & 1) * 64;
    const int lrow = lane & 15, lk8 = (lane >> 4) * 8;
    const int wbase = wave * 64;

    floatx4 acc[4][4] = {};

    const uint16_t* aT = A  + (size_t)m0 * K;
    const uint16_t* bT = Bt + (size_t)n0 * K;

    for (int k0 = 0; k0 < K; k0 += 32) {
        __syncthreads();
#pragma unroll
        for (int i = 0; i < 2; ++i) {
            const int cw = i * 256 + wbase;      // wave-uniform chunk base
            const int c  = cw + lane;
            const int row = c >> 2, kc = (c & 3) * 8;
            gload_lds16(aT + (size_t)row * K + k0 + kc, &lA[cw * 8]);
            gload_lds16(bT + (size_t)row * K + k0 + kc, &lB[cw * 8]);
        }
        __syncthreads();
        bf16x8 af[4], bfr[4];
#pragma unroll
        for (int mi = 0; mi < 4; ++mi)
            af[mi] = *(const bf16x8*)&lA[(wm + mi * 16 + lrow) * 32 + lk8];
#pragma unroll
        for (int ni = 0; ni < 4; ++ni)
            bfr[ni] = *(const bf16x8*)&lB[(wn + ni * 16 + lrow) * 32 + lk8];
#pragma unroll
        for (int mi = 0; mi < 4; ++mi)
#pragma unroll
            for (int ni = 0; ni < 4; ++ni)
                acc[mi][ni] = __builtin_amdgcn_mfma_f32_16x16x32_bf16(
                    af[mi], bfr[ni], acc[mi][ni], 0, 0, 0);
    }

    const int r0 = (lane >> 4) * 4;
#pragma unroll
    for (int ni = 0; ni < 4; ++ni) {
        const int col = n0 + wn + ni * 16 + lrow;
        const float bv = bias[col];
#pragma unroll
        for (int mi = 0; mi < 4; ++mi) {
#pragma unroll
            for (int r = 0; r < 4; ++r) {
                const int row = m0 + wm + mi * 16 + r0 + r;
                const size_t idx = (size_t)row * N + col;
                float v = acc[mi][ni][r] + bv;
                if (mode == 1) {
                    outF[idx] = v + resid[idx];
                } else if (mode == 2) {
                    outB[idx] = f2b(0.5f * v * (1.0f + erff(v * 0.70710678118654752f)));
                } else {
                    outB[idx] = f2b(v);
                }
            }
        }
    }
}

// ---------------------------------------------------------------------------
// Flash attention v3 (causal, work-balanced).
// Grid (4, 16, 4) = 256 blocks = exactly 1/CU, all uniform work:
//   block x processes q-tiles (7-x) then (x)  [256 rows each] -> 36 K-tiles.
// 256 thr = 4 waves; wave w owns 64 q-rows of the current q-tile.
// K/V 64x64 tiles staged via global_load_lds, double-buffered, XOR-swizzled.
// Wq/bq pre-scaled by 0.125*log2(e): softmax natively in exp2 domain.
// Reductions via DPP row_ror (VALU pipe, no LDS). bf16 cvt via HW v_cvt.
// ---------------------------------------------------------------------------
__global__ __launch_bounds__(256, 1) void attn_kernel(
    const uint16_t* __restrict__ qkv, const uint16_t* __restrict__ Vt,
    uint16_t* __restrict__ ctx)
{
    const int h = blockIdx.y, b = blockIdx.z;
    const int tid = threadIdx.x, wave = tid >> 6, lane = tid & 63;
    const int quad = lane >> 4, lcol = lane & 15, lr4 = quad * 4;
    const int sx = lcol & 7;
    const uint16_t* qbase = qkv + (size_t)b * 2048 * 3072;
    const uint16_t* kgb = qbase + 1024 + h * 64;
    const uint16_t* vtb = Vt + (size_t)(b * 16 + h) * 64 * 2048;

    __shared__ __align__(16) uint16_t kbuf[2][64 * 64];
    __shared__ __align__(16) uint16_t vbuf[2][64 * 64];
    __shared__ __align__(16) uint16_t pshm[4][64 * 64];

    const int rr = lane >> 3, sl = lane & 7;
    const int swz = sl ^ rr;                 // global 16B-chunk this lane fetches

#define STAGE(ktile, bb)                                                        \
    {                                                                           \
        const int _kb = (ktile) * 64;                                           \
        _Pragma("unroll")                                                       \
        for (int i = 0; i < 2; ++i) {                                           \
            const int j = wave * 2 + i;                                         \
            const int r = j * 8 + rr;                                           \
            gload_lds16(kgb + (size_t)(_kb + r) * 3072 + swz * 8,               \
                        &kbuf[bb][j * 512]);                                    \
            gload_lds16(vtb + (size_t)r * 2048 + _kb + swz * 8,                 \
                        &vbuf[bb][j * 512]);                                    \
        }                                                                       \
    }

    for (int pp = 0; pp < 2; ++pp) {
        const int qt = pp ? (int)blockIdx.x : 7 - (int)blockIdx.x;  // heavy first
        const int qr0 = qt * 256 + wave * 64;

        // Q fragments (A-layout): m = lcol, k = quad*8+j (+32 second chunk)
        bf16x8 qf[4][2];
#pragma unroll
        for (int mi = 0; mi < 4; ++mi) {
            const uint16_t* qp = qbase + (size_t)(qr0 + mi * 16 + lcol) * 3072 + h * 64;
            qf[mi][0] = *(const bf16x8*)(qp + quad * 8);
            qf[mi][1] = *(const bf16x8*)(qp + 32 + quad * 8);
        }

        floatx4 o[4][4] = {};
        float m_i[4][4], l_i[4][4];
#pragma unroll
        for (int mi = 0; mi < 4; ++mi)
#pragma unroll
            for (int r = 0; r < 4; ++r) { m_i[mi][r] = -1e30f; l_i[mi][r] = 0.f; }

        const int nk = 4 * qt + 4;
        __syncthreads();                       // prior pass done with buffers
        STAGE(0, 0);
        int cur = 0;

        for (int kt = 0; kt < nk; ++kt) {
            const int kb = kt * 64;
            __syncthreads();                   // drains vmcnt: buf[cur] ready
            if (kt + 1 < nk) STAGE(kt + 1, cur ^ 1);

            if (kb <= qr0 + 63) {              // wave-uniform causal skip
                bf16x8 kf[4][2];
#pragma unroll
                for (int nt = 0; nt < 4; ++nt) {
                    const int krow = nt * 16 + lcol;
                    kf[nt][0] = *(const bf16x8*)&kbuf[cur][krow * 64 + ((quad ^ sx) * 8)];
                    kf[nt][1] = *(const bf16x8*)&kbuf[cur][krow * 64 + (((quad + 4) ^ sx) * 8)];
                }
#pragma unroll
                for (int mi = 0; mi < 4; ++mi) {
                    floatx4 sv[4];
#pragma unroll
                    for (int nt = 0; nt < 4; ++nt) {
                        floatx4 s = {0.f, 0.f, 0.f, 0.f};
                        s = __builtin_amdgcn_mfma_f32_16x16x32_bf16(qf[mi][0], kf[nt][0], s, 0, 0, 0);
                        s = __builtin_amdgcn_mfma_f32_16x16x32_bf16(qf[mi][1], kf[nt][1], s, 0, 0, 0);
                        sv[nt] = s;
                    }
                    if (kb + 63 > qr0 + mi * 16) {     // causal mask needed
#pragma unroll
                        for (int nt = 0; nt < 4; ++nt)
#pragma unroll
                            for (int r = 0; r < 4; ++r) {
                                const int row = qr0 + mi * 16 + lr4 + r;
                                const int col = kb + nt * 16 + lcol;
                                if (col > row) sv[nt][r] = -1e30f;
                            }
                    }
#pragma unroll
                    for (int r = 0; r < 4; ++r) {
                        float m = fmaxf(fmaxf(sv[0][r], sv[1][r]),
                                        fmaxf(sv[2][r], sv[3][r]));
                        m = rowmax16(m);
                        const float mn = fmaxf(m_i[mi][r], m);
                        const float alpha = __builtin_amdgcn_exp2f(m_i[mi][r] - mn);
                        m_i[mi][r] = mn;
                        const int row = mi * 16 + lr4 + r;
                        const int rsw = row & 7;
                        float l = 0.f;
#pragma unroll
                        for (int nt = 0; nt < 4; ++nt) {
                            const float p = __builtin_amdgcn_exp2f(sv[nt][r] - mn);
                            l += p;
                            const int col = nt * 16 + lcol;
                            pshm[wave][row * 64 + (((col >> 3) ^ rsw) * 8) + (col & 7)] =
                                bf16bits(p);
                        }
                        l = rowsum16(l);
                        l_i[mi][r] = l_i[mi][r] * alpha + l;
#pragma unroll
                        for (int ht = 0; ht < 4; ++ht) o[mi][ht][r] *= alpha;
                    }
                }
                // P (A-layout) fragments from pshm
                bf16x8 pf[4][2];
#pragma unroll
                for (int mi = 0; mi < 4; ++mi) {
                    const int prow = mi * 16 + lcol;
                    pf[mi][0] = *(const bf16x8*)&pshm[wave][prow * 64 + ((quad ^ sx) * 8)];
                    pf[mi][1] = *(const bf16x8*)&pshm[wave][prow * 64 + (((quad + 4) ^ sx) * 8)];
                }
#pragma unroll
                for (int ht = 0; ht < 4; ++ht) {
                    const int hd = ht * 16 + lcol;
                    const bf16x8 vf0 = *(const bf16x8*)&vbuf[cur][hd * 64 + ((quad ^ sx) * 8)];
                    const bf16x8 vf1 = *(const bf16x8*)&vbuf[cur][hd * 64 + (((quad + 4) ^ sx) * 8)];
#pragma unroll
                    for (int mi = 0; mi < 4; ++mi) {
                        o[mi][ht] = __builtin_amdgcn_mfma_f32_16x16x32_bf16(pf[mi][0], vf0, o[mi][ht], 0, 0, 0);
                        o[mi][ht] = __builtin_amdgcn_mfma_f32_16x16x32_bf16(pf[mi][1], vf1, o[mi][ht], 0, 0, 0);
                    }
                }
            }
            cur ^= 1;
        }

#pragma unroll
        for (int mi = 0; mi < 4; ++mi)
#pragma unroll
            for (int r = 0; r < 4; ++r) {
                const float inv = 1.0f / l_i[mi][r];
                const int row = qr0 + mi * 16 + lr4 + r;
#pragma unroll
                for (int ht = 0; ht < 4; ++ht)
                    ctx[(size_t)(b * 2048 + row) * 1024 + h * 64 + ht * 16 + lcol] =
                        bf16bits(o[mi][ht][r] * inv);
            }
    }
#undef STAGE
}

// ---------------------------------------------------------------------------
// Launch
// ---------------------------------------------------------------------------
extern "C" void kernel_launch(void* const* d_in, const int* in_sizes, int n_in,
                              void* d_out, int out_size, void* d_ws, size_t ws_size,
                              hipStream_t stream)
{
    (void)in_sizes; (void)n_in; (void)out_size; (void)ws_size;
    const float* x     = (const float*)d_in[0];
    const float* ln1_g = (const float*)d_in[2];
    const float* ln1_b = (const float*)d_in[3];
    const float* Wq    = (const float*)d_in[4];
    const float* bq    = (const float*)d_in[5];
    const float* Wk    = (const float*)d_in[6];
    const float* bk    = (const float*)d_in[7];
    const float* Wv    = (const float*)d_in[8];
    const float* bv    = (const float*)d_in[9];
    const float* Wo    = (const float*)d_in[10];
    const float* bo    = (const float*)d_in[11];
    const float* ln2_g = (const float*)d_in[12];
    const float* ln2_b = (const float*)d_in[13];
    const float* W1    = (const float*)d_in[14];
    const float* b1    = (const float*)d_in[15];
    const float* W2    = (const float*)d_in[16];
    const float* b2    = (const float*)d_in[17];
    float* out = (float*)d_out;

    char* w = (char*)d_ws;
    uint16_t* Wqkv_t = (uint16_t*)w;  w += 6291456;    // [3072][1024]
    uint16_t* Wo_t   = (uint16_t*)w;  w += 2097152;    // [1024][1024]
    uint16_t* W1_t   = (uint16_t*)w;  w += 8388608;    // [4096][1024]
    uint16_t* W2_t   = (uint16_t*)w;  w += 8388608;    // [1024][4096]
    float*    bqkv   = (float*)w;     w += 16384;      // [3072]
    float*    x2     = (float*)w;     w += 33554432;   // [8192][1024] fp32
    char* region = w;
    uint16_t* hbuf = (uint16_t*)region;                        // 16MB h, later ctx
    uint16_t* qkv  = (uint16_t*)(region + 16777216);           // 48MB
    uint16_t* Vt   = (uint16_t*)(region + 16777216 + 50331648);// 16MB
    uint16_t* ctx  = hbuf;
    uint16_t* h2   = (uint16_t*)region;
    uint16_t* a1   = (uint16_t*)(region + 16777216);

    repack_qkv<<<dim3(32, 2, 48), 256, 0, stream>>>(Wq, Wk, Wv, Wqkv_t);
    transpose_f2b<<<dim3(32, 32),  256, 0, stream>>>(Wo, Wo_t, 1024, 1024);
    transpose_f2b<<<dim3(128, 32), 256, 0, stream>>>(W1, W1_t, 1024, 4096);
    transpose_f2b<<<dim3(32, 128), 256, 0, stream>>>(W2, W2_t, 4096, 1024);
    concat_bias<<<12, 256, 0, stream>>>(bq, bk, bv, bqkv);
    ln_bf16<<<8192, 256, 0, stream>>>(x, ln1_g, ln1_b, hbuf);
    gemm_bf16<<<dim3(24, 64), 256, 0, stream>>>(hbuf, Wqkv_t, 8192, 3072, 1024,
                                                bqkv, nullptr, nullptr, qkv, 0);
    transpose_v<<<dim3(64, 2, 64), 256, 0, stream>>>(qkv, Vt);
    attn_kernel<<<dim3(4, 16, 4), 256, 0, stream>>>(qkv, Vt, ctx);
    gemm_bf16<<<dim3(8, 64), 256, 0, stream>>>(ctx, Wo_t, 8192, 1024, 1024,
                                               bo, x, x2, nullptr, 1);
    ln_bf16<<<8192, 256, 0, stream>>>(x2, ln2_g, ln2_b, h2);
    gemm_bf16<<<dim3(32, 64), 256, 0, stream>>>(h2, W1_t, 8192, 4096, 1024,
                                                b1, nullptr, nullptr, a1, 2);
    gemm_bf16<<<dim3(8, 64), 256, 0, stream>>>(a1, W2_t, 8192, 1024, 4096,
                                               b2, x2, out, nullptr, 1);
}

// Round 4
// 581.323 us; speedup vs baseline: 1.7262x; 1.2045x over previous
//
#include <hip/hip_runtime.h>
#include <cstdint>
#include <cstddef>

// ---------------------------------------------------------------------------
// Types / helpers
// ---------------------------------------------------------------------------
typedef __bf16 bf16x8 __attribute__((ext_vector_type(8)));
typedef float  floatx4 __attribute__((ext_vector_type(4)));

__device__ __forceinline__ uint16_t f2b(float f) {
    uint32_t u = __builtin_bit_cast(uint32_t, f);
    return (uint16_t)((u + 0x7fffu + ((u >> 16) & 1)) >> 16);  // RNE
}

__device__ __forceinline__ uint16_t bf16bits(float f) {       // HW v_cvt (RNE)
    __bf16 h = (__bf16)f;
    return __builtin_bit_cast(uint16_t, h);
}

__device__ __forceinline__ void gload_lds16(const void* g, void* l) {
    __builtin_amdgcn_global_load_lds(
        (__attribute__((address_space(1))) void*)(void*)g,
        (__attribute__((address_space(3))) void*)l, 16, 0, 0);
}

// DPP row_ror helpers: 16-lane-row reductions entirely in the VALU pipe.
template<int CTRL>
__device__ __forceinline__ float dpp_rot(float v) {
    return __builtin_bit_cast(float,
        __builtin_amdgcn_update_dpp(0, __builtin_bit_cast(int, v),
                                    CTRL, 0xf, 0xf, true));
}
__device__ __forceinline__ float rowmax16(float v) {
    v = fmaxf(v, dpp_rot<0x128>(v));
    v = fmaxf(v, dpp_rot<0x124>(v));
    v = fmaxf(v, dpp_rot<0x122>(v));
    v = fmaxf(v, dpp_rot<0x121>(v));
    return v;
}
__device__ __forceinline__ float rowsum16(float v) {
    v += dpp_rot<0x128>(v);
    v += dpp_rot<0x124>(v);
    v += dpp_rot<0x122>(v);
    v += dpp_rot<0x121>(v);
    return v;
}

// 0.125 (1/sqrt(HD)) * log2(e): folded into Wq/bq so softmax is exp2-domain.
#define QSCALE 0.18033688011112042f

// ---------------------------------------------------------------------------
// Weight repack kernels (fp32 -> bf16, transposed to [N][K])
// ---------------------------------------------------------------------------
__global__ __launch_bounds__(256) void repack_qkv(
    const float* __restrict__ Wq, const float* __restrict__ Wk,
    const float* __restrict__ Wv, uint16_t* __restrict__ out)
{
    __shared__ uint16_t tile[32][33];
    const int m = blockIdx.z >> 4, h = blockIdx.z & 15;
    const float* W = (m == 0) ? Wq : (m == 1) ? Wk : Wv;
    const float scl = (m == 0) ? QSCALE : 1.0f;
    const float* src = W + (size_t)h * 1024 * 64;           // [1024][64]
    const int d0 = blockIdx.x * 32, hd0 = blockIdx.y * 32;
    const int tx = threadIdx.x & 31, ty = threadIdx.x >> 5;
#pragma unroll
    for (int i = 0; i < 4; ++i)
        tile[ty + i * 8][tx] = f2b(src[(size_t)(d0 + ty + i * 8) * 64 + hd0 + tx] * scl);
    __syncthreads();
    uint16_t* dst = out + (size_t)(m * 1024 + h * 64) * 1024; // [64][1024]
#pragma unroll
    for (int i = 0; i < 4; ++i)
        dst[(size_t)(hd0 + ty + i * 8) * 1024 + d0 + tx] = tile[tx][ty + i * 8];
}

__global__ __launch_bounds__(256) void transpose_f2b(
    const float* __restrict__ in, uint16_t* __restrict__ out, int R, int C)
{
    __shared__ uint16_t tile[32][33];
    const int c0 = blockIdx.x * 32, r0 = blockIdx.y * 32;
    const int tx = threadIdx.x & 31, ty = threadIdx.x >> 5;
#pragma unroll
    for (int i = 0; i < 4; ++i)
        tile[ty + i * 8][tx] = f2b(in[(size_t)(r0 + ty + i * 8) * C + c0 + tx]);
    __syncthreads();
#pragma unroll
    for (int i = 0; i < 4; ++i)
        out[(size_t)(c0 + ty + i * 8) * R + r0 + tx] = tile[tx][ty + i * 8];
}

__global__ void concat_bias(const float* __restrict__ bq, const float* __restrict__ bk,
                            const float* __restrict__ bv, float* __restrict__ out)
{
    int i = blockIdx.x * 256 + threadIdx.x;  // 3072 total
    out[i] = (i < 1024) ? bq[i] * QSCALE : (i < 2048) ? bk[i - 1024] : bv[i - 2048];
}

// V slice of qkv [B*T][3072] (cols 2048+h*64+hd) -> Vt [(b*16+h)*64+hd][2048]
__global__ __launch_bounds__(256) void transpose_v(
    const uint16_t* __restrict__ qkv, uint16_t* __restrict__ Vt)
{
    __shared__ uint16_t tile[32][33];
    const int bh = blockIdx.z;
    const int b = bh >> 4, h = bh & 15;
    const int t0 = blockIdx.x * 32, hd0 = blockIdx.y * 32;
    const int tx = threadIdx.x & 31, ty = threadIdx.x >> 5;
    const uint16_t* src = qkv + (size_t)b * 2048 * 3072 + 2048 + h * 64;
#pragma unroll
    for (int i = 0; i < 4; ++i)
        tile[ty + i * 8][tx] = src[(size_t)(t0 + ty + i * 8) * 3072 + hd0 + tx];
    __syncthreads();
    uint16_t* dst = Vt + (size_t)bh * 64 * 2048;
#pragma unroll
    for (int i = 0; i < 4; ++i)
        dst[(size_t)(hd0 + ty + i * 8) * 2048 + t0 + tx] = tile[tx][ty + i * 8];
}

// ---------------------------------------------------------------------------
// LayerNorm: fp32 [rows][1024] -> bf16, one block per row
// ---------------------------------------------------------------------------
__global__ __launch_bounds__(256) void ln_bf16(
    const float* __restrict__ x, const float* __restrict__ g,
    const float* __restrict__ b, uint16_t* __restrict__ out)
{
    const int row = blockIdx.x;
    const int t = threadIdx.x;
    const float4 v = ((const float4*)(x + (size_t)row * 1024))[t];
    float s  = v.x + v.y + v.z + v.w;
    float s2 = v.x * v.x + v.y * v.y + v.z * v.z + v.w * v.w;
#pragma unroll
    for (int o = 32; o > 0; o >>= 1) { s += __shfl_down(s, o); s2 += __shfl_down(s2, o); }
    __shared__ float red[8];
    const int wave = t >> 6, lane = t & 63;
    if (lane == 0) { red[wave] = s; red[4 + wave] = s2; }
    __syncthreads();
    if (t == 0) {
        float a  = red[0] + red[1] + red[2] + red[3];
        float a2 = red[4] + red[5] + red[6] + red[7];
        float mu = a * (1.0f / 1024.0f);
        red[0] = mu;
        red[4] = rsqrtf(a2 * (1.0f / 1024.0f) - mu * mu + 1e-5f);
    }
    __syncthreads();
    const float mu = red[0], rs = red[4];
    const float4 gv = ((const float4*)g)[t];
    const float4 bv = ((const float4*)b)[t];
    ushort4 ov;
    ov.x = f2b((v.x - mu) * rs * gv.x + bv.x);
    ov.y = f2b((v.y - mu) * rs * gv.y + bv.y);
    ov.z = f2b((v.z - mu) * rs * gv.z + bv.z);
    ov.w = f2b((v.w - mu) * rs * gv.w + bv.w);
    ((ushort4*)(out + (size_t)row * 1024))[t] = ov;
}

// ---------------------------------------------------------------------------
// GEMM: C[M,N] = A[M,K](bf16,rowmajor) * Bt[N,K](bf16,rowmajor)^T + bias
// mode 0: out bf16            mode 1: out fp32 + resid      mode 2: bf16 gelu
// 128x128x32 tiles. 8x8-block supertile swizzle: the 64 consecutive HW block
// ids covering a 1024x1024 C region share a 2MB A-slice + 2MB B-slice per
// XCD L2. Epilogue staged through LDS (bank-swizzled) for full-line stores.
// ---------------------------------------------------------------------------
__global__ __launch_bounds__(256, 2) void gemm_bf16(
    const uint16_t* __restrict__ A, const uint16_t* __restrict__ Bt,
    int M, int N, int K,
    const float* __restrict__ bias, const float* __restrict__ resid,
    float* __restrict__ outF, uint16_t* __restrict__ outB, int mode)
{
    __shared__ __align__(16) uint16_t lds[128 * 128];   // 32KB: staging + epilogue
    uint16_t* lA = lds;                                  // 128*32 (8KB)
    uint16_t* lB = lds + 128 * 32;                       // 8KB
    const int tid  = threadIdx.x;
    const int wave = tid >> 6, lane = tid & 63;

    // supertile remap (gridDim.x % 8 == 0, gridDim.y % 8 == 0)
    const int lid = (int)blockIdx.y * (int)gridDim.x + (int)blockIdx.x;
    const int superPerRow = (int)gridDim.x >> 3;
    const int superIdx = lid >> 6, inS = lid & 63;
    const int sRow = superIdx / superPerRow, sCol = superIdx % superPerRow;
    const int m0 = (sRow * 8 + (inS >> 3)) * 128;
    const int n0 = (sCol * 8 + (inS & 7)) * 128;

    const int wm = (wave >> 1) * 64, wn = (wave & 1) * 64;
    const int lrow = lane & 15, lk8 = (lane >> 4) * 8;
    const int wbase = wave * 64;

    floatx4 acc[4][4] = {};

    const uint16_t* aT = A  + (size_t)m0 * K;
    const uint16_t* bT = Bt + (size_t)n0 * K;

    for (int k0 = 0; k0 < K; k0 += 32) {
        __syncthreads();
#pragma unroll
        for (int i = 0; i < 2; ++i) {
            const int cw = i * 256 + wbase;      // wave-uniform chunk base
            const int c  = cw + lane;
            const int row = c >> 2, kc = (c & 3) * 8;
            gload_lds16(aT + (size_t)row * K + k0 + kc, &lA[cw * 8]);
            gload_lds16(bT + (size_t)row * K + k0 + kc, &lB[cw * 8]);
        }
        __syncthreads();
        bf16x8 af[4], bfr[4];
#pragma unroll
        for (int mi = 0; mi < 4; ++mi)
            af[mi] = *(const bf16x8*)&lA[(wm + mi * 16 + lrow) * 32 + lk8];
#pragma unroll
        for (int ni = 0; ni < 4; ++ni)
            bfr[ni] = *(const bf16x8*)&lB[(wn + ni * 16 + lrow) * 32 + lk8];
#pragma unroll
        for (int mi = 0; mi < 4; ++mi)
#pragma unroll
            for (int ni = 0; ni < 4; ++ni)
                acc[mi][ni] = __builtin_amdgcn_mfma_f32_16x16x32_bf16(
                    af[mi], bfr[ni], acc[mi][ni], 0, 0, 0);
    }

    __syncthreads();                           // staging buffers free now
    const int r0 = (lane >> 4) * 4;

    if (mode == 1) {
        // fp32 + residual, two 64-row passes staged in LDS (32KB fp32)
        float* cf = (float*)lds;
#pragma unroll
        for (int p = 0; p < 2; ++p) {
            if ((wave >> 1) == p) {
#pragma unroll
                for (int ni = 0; ni < 4; ++ni) {
                    const int col = wn + ni * 16 + lrow;
                    const float bv = bias[n0 + col];
#pragma unroll
                    for (int mi = 0; mi < 4; ++mi)
#pragma unroll
                        for (int r = 0; r < 4; ++r) {
                            const int row = mi * 16 + r0 + r;       // 0..63
                            const int g = (col >> 2) ^ (((row >> 2) & 1) << 2);
                            cf[row * 128 + g * 4 + (col & 3)] = acc[mi][ni][r] + bv;
                        }
                }
            }
            __syncthreads();
#pragma unroll
            for (int i = 0; i < 8; ++i) {
                const int ci = i * 256 + tid;        // 16B chunk id
                const int row = ci >> 5, cg = ci & 31;
                const int g = cg ^ (((row >> 2) & 1) << 2);
                float4 v = *(const float4*)&cf[row * 128 + g * 4];
                const size_t gidx = (size_t)(m0 + p * 64 + row) * N + n0 + cg * 4;
                const float4 rz = *(const float4*)&resid[gidx];
                v.x += rz.x; v.y += rz.y; v.z += rz.z; v.w += rz.w;
                *(float4*)&outF[gidx] = v;
            }
            __syncthreads();
        }
    } else {
        // bf16 out (mode 0 plain / mode 2 gelu), full 128x128 tile in LDS
#pragma unroll
        for (int ni = 0; ni < 4; ++ni) {
            const int col = wn + ni * 16 + lrow;
            const float bv = bias[n0 + col];
#pragma unroll
            for (int mi = 0; mi < 4; ++mi)
#pragma unroll
                for (int r = 0; r < 4; ++r) {
                    const int row = wm + mi * 16 + r0 + r;
                    float v = acc[mi][ni][r] + bv;
                    if (mode == 2)
                        v = 0.5f * v * (1.0f + erff(v * 0.70710678118654752f));
                    const int g = (col >> 3) ^ (((row >> 2) & 3) << 1);
                    lds[row * 128 + g * 8 + (col & 7)] = bf16bits(v);
                }
        }
        __syncthreads();
#pragma unroll
        for (int i = 0; i < 8; ++i) {
            const int ci = i * 256 + tid;            // 16B chunk id
            const int row = ci >> 4, cg = ci & 15;
            const int g = cg ^ (((row >> 2) & 3) << 1);
            const bf16x8 v = *(const bf16x8*)&lds[row * 128 + g * 8];
            *(bf16x8*)&outB[(size_t)(m0 + row) * N + n0 + cg * 8] = v;
        }
    }
}

// ---------------------------------------------------------------------------
// Flash attention v4 (causal, balanced, 2 blocks/CU).
// Grid (8, 16, 4) = 512 blocks; block x does q-tiles (15-x) then (x), 128
// rows each -> uniform 34 K-tiles/block. 4 waves; wave owns 32 q-rows.
// K/V 64x64 tiles staged via global_load_lds, double-buffered, XOR-swizzled.
// Softmax natively exp2-domain (scale folded into Wq/bq); DPP reductions.
// LDS 48KB/block -> 2 blocks/CU co-resident (softmax VALU of one block
// overlaps MFMA/LDS of the other).
// ---------------------------------------------------------------------------
__global__ __launch_bounds__(256, 2) void attn_kernel(
    const uint16_t* __restrict__ qkv, const uint16_t* __restrict__ Vt,
    uint16_t* __restrict__ ctx)
{
    const int h = blockIdx.y, b = blockIdx.z;
    const int tid = threadIdx.x, wave = tid >> 6, lane = tid & 63;
    const int quad = lane >> 4, lcol = lane & 15, lr4 = quad * 4;
    const int sx = lcol & 7;
    const uint16_t* qbase = qkv + (size_t)b * 2048 * 3072;
    const uint16_t* kgb = qbase + 1024 + h * 64;
    const uint16_t* vtb = Vt + (size_t)(b * 16 + h) * 64 * 2048;

    __shared__ __align__(16) uint16_t kbuf[2][64 * 64];
    __shared__ __align__(16) uint16_t vbuf[2][64 * 64];
    __shared__ __align__(16) uint16_t pshm[4][32 * 64];

    const int rr = lane >> 3, sl = lane & 7;
    const int swz = sl ^ rr;                 // global 16B-chunk this lane fetches

#define STAGE(ktile, bb)                                                        \
    {                                                                           \
        const int _kb = (ktile) * 64;                                           \
        _Pragma("unroll")                                                       \
        for (int i = 0; i < 2; ++i) {                                           \
            const int j = wave * 2 + i;                                         \
            const int r = j * 8 + rr;                                           \
            gload_lds16(kgb + (size_t)(_kb + r) * 3072 + swz * 8,               \
                        &kbuf[bb][j * 512]);                                    \
            gload_lds16(vtb + (size_t)r * 2048 + _kb + swz * 8,                 \
                        &vbuf[bb][j * 512]);                                    \
        }                                                                       \
    }

    for (int pp = 0; pp < 2; ++pp) {
        const int qt = pp ? (int)blockIdx.x : 15 - (int)blockIdx.x;
        const int qr0 = qt * 128 + wave * 32;

        // Q fragments (A-layout): m = lcol, k = quad*8+j (+32 second chunk)
        bf16x8 qf[2][2];
#pragma unroll
        for (int mi = 0; mi < 2; ++mi) {
            const uint16_t* qp = qbase + (size_t)(qr0 + mi * 16 + lcol) * 3072 + h * 64;
            qf[mi][0] = *(const bf16x8*)(qp + quad * 8);
            qf[mi][1] = *(const bf16x8*)(qp + 32 + quad * 8);
        }

        floatx4 o[2][4] = {};
        float m_i[2][4], l_i[2][4];
#pragma unroll
        for (int mi = 0; mi < 2; ++mi)
#pragma unroll
            for (int r = 0; r < 4; ++r) { m_i[mi][r] = -1e30f; l_i[mi][r] = 0.f; }

        const int nk = 2 * qt + 2;
        __syncthreads();                       // prior pass done with buffers
        STAGE(0, 0);
        int cur = 0;

        for (int kt = 0; kt < nk; ++kt) {
            const int kb = kt * 64;
            __syncthreads();                   // drains vmcnt: buf[cur] ready
            if (kt + 1 < nk) STAGE(kt + 1, cur ^ 1);

            if (kb <= qr0 + 31) {              // wave-uniform causal skip
                bf16x8 kf[4][2];
#pragma unroll
                for (int nt = 0; nt < 4; ++nt) {
                    const int krow = nt * 16 + lcol;
                    kf[nt][0] = *(const bf16x8*)&kbuf[cur][krow * 64 + ((quad ^ sx) * 8)];
                    kf[nt][1] = *(const bf16x8*)&kbuf[cur][krow * 64 + (((quad + 4) ^ sx) * 8)];
                }
#pragma unroll
                for (int mi = 0; mi < 2; ++mi) {
                    floatx4 sv[4];
#pragma unroll
                    for (int nt = 0; nt < 4; ++nt) {
                        floatx4 s = {0.f, 0.f, 0.f, 0.f};
                        s = __builtin_amdgcn_mfma_f32_16x16x32_bf16(qf[mi][0], kf[nt][0], s, 0, 0, 0);
                        s = __builtin_amdgcn_mfma_f32_16x16x32_bf16(qf[mi][1], kf[nt][1], s, 0, 0, 0);
                        sv[nt] = s;
                    }
                    if (kb + 63 > qr0 + mi * 16) {     // causal mask needed
#pragma unroll
                        for (int nt = 0; nt < 4; ++nt)
#pragma unroll
                            for (int r = 0; r < 4; ++r) {
                                const int row = qr0 + mi * 16 + lr4 + r;
                                const int col = kb + nt * 16 + lcol;
                                if (col > row) sv[nt][r] = -1e30f;
                            }
                    }
#pragma unroll
                    for (int r = 0; r < 4; ++r) {
                        float m = fmaxf(fmaxf(sv[0][r], sv[1][r]),
                                        fmaxf(sv[2][r], sv[3][r]));
                        m = rowmax16(m);
                        const float mn = fmaxf(m_i[mi][r], m);
                        const float alpha = __builtin_amdgcn_exp2f(m_i[mi][r] - mn);
                        m_i[mi][r] = mn;
                        const int row = mi * 16 + lr4 + r;
                        const int rsw = row & 7;
                        float l = 0.f;
#pragma unroll
                        for (int nt = 0; nt < 4; ++nt) {
                            const float p = __builtin_amdgcn_exp2f(sv[nt][r] - mn);
                            l += p;
                            const int col = nt * 16 + lcol;
                            pshm[wave][row * 64 + (((col >> 3) ^ rsw) * 8) + (col & 7)] =
                                bf16bits(p);
                        }
                        l = rowsum16(l);
                        l_i[mi][r] = l_i[mi][r] * alpha + l;
#pragma unroll
                        for (int ht = 0; ht < 4; ++ht) o[mi][ht][r] *= alpha;
                    }
                }
                // P (A-layout) fragments from pshm
                bf16x8 pf[2][2];
#pragma unroll
                for (int mi = 0; mi < 2; ++mi) {
                    const int prow = mi * 16 + lcol;
                    pf[mi][0] = *(const bf16x8*)&pshm[wave][prow * 64 + ((quad ^ sx) * 8)];
                    pf[mi][1] = *(const bf16x8*)&pshm[wave][prow * 64 + (((quad + 4) ^ sx) * 8)];
                }
#pragma unroll
                for (int ht = 0; ht < 4; ++ht) {
                    const int hd = ht * 16 + lcol;
                    const bf16x8 vf0 = *(const bf16x8*)&vbuf[cur][hd * 64 + ((quad ^ sx) * 8)];
                    const bf16x8 vf1 = *(const bf16x8*)&vbuf[cur][hd * 64 + (((quad + 4) ^ sx) * 8)];
#pragma unroll
                    for (int mi = 0; mi < 2; ++mi) {
                        o[mi][ht] = __builtin_amdgcn_mfma_f32_16x16x32_bf16(pf[mi][0], vf0, o[mi][ht], 0, 0, 0);
                        o[mi][ht] = __builtin_amdgcn_mfma_f32_16x16x32_bf16(pf[mi][1], vf1, o[mi][ht], 0, 0, 0);
                    }
                }
            }
            cur ^= 1;
        }

#pragma unroll
        for (int mi = 0; mi < 2; ++mi)
#pragma unroll
            for (int r = 0; r < 4; ++r) {
                const float inv = 1.0f / l_i[mi][r];
                const int row = qr0 + mi * 16 + lr4 + r;
#pragma unroll
                for (int ht = 0; ht < 4; ++ht)
                    ctx[(size_t)(b * 2048 + row) * 1024 + h * 64 + ht * 16 + lcol] =
                        bf16bits(o[mi][ht][r] * inv);
            }
    }
#undef STAGE
}

// ---------------------------------------------------------------------------
// Launch
// ---------------------------------------------------------------------------
extern "C" void kernel_launch(void* const* d_in, const int* in_sizes, int n_in,
                              void* d_out, int out_size, void* d_ws, size_t ws_size,
                              hipStream_t stream)
{
    (void)in_sizes; (void)n_in; (void)out_size; (void)ws_size;
    const float* x     = (const float*)d_in[0];
    const float* ln1_g = (const float*)d_in[2];
    const float* ln1_b = (const float*)d_in[3];
    const float* Wq    = (const float*)d_in[4];
    const float* bq    = (const float*)d_in[5];
    const float* Wk    = (const float*)d_in[6];
    const float* bk    = (const float*)d_in[7];
    const float* Wv    = (const float*)d_in[8];
    const float* bv    = (const float*)d_in[9];
    const float* Wo    = (const float*)d_in[10];
    const float* bo    = (const float*)d_in[11];
    const float* ln2_g = (const float*)d_in[12];
    const float* ln2_b = (const float*)d_in[13];
    const float* W1    = (const float*)d_in[14];
    const float* b1    = (const float*)d_in[15];
    const float* W2    = (const float*)d_in[16];
    const float* b2    = (const float*)d_in[17];
    float* out = (float*)d_out;

    char* w = (char*)d_ws;
    uint16_t* Wqkv_t = (uint16_t*)w;  w += 6291456;    // [3072][1024]
    uint16_t* Wo_t   = (uint16_t*)w;  w += 2097152;    // [1024][1024]
    uint16_t* W1_t   = (uint16_t*)w;  w += 8388608;    // [4096][1024]
    uint16_t* W2_t   = (uint16_t*)w;  w += 8388608;    // [1024][4096]
    float*    bqkv   = (float*)w;     w += 16384;      // [3072]
    float*    x2     = (float*)w;     w += 33554432;   // [8192][1024] fp32
    char* region = w;
    uint16_t* hbuf = (uint16_t*)region;                        // 16MB h, later ctx
    uint16_t* qkv  = (uint16_t*)(region + 16777216);           // 48MB
    uint16_t* Vt   = (uint16_t*)(region + 16777216 + 50331648);// 16MB
    uint16_t* ctx  = hbuf;
    uint16_t* h2   = (uint16_t*)region;
    uint16_t* a1   = (uint16_t*)(region + 16777216);

    repack_qkv<<<dim3(32, 2, 48), 256, 0, stream>>>(Wq, Wk, Wv, Wqkv_t);
    transpose_f2b<<<dim3(32, 32),  256, 0, stream>>>(Wo, Wo_t, 1024, 1024);
    transpose_f2b<<<dim3(128, 32), 256, 0, stream>>>(W1, W1_t, 1024, 4096);
    transpose_f2b<<<dim3(32, 128), 256, 0, stream>>>(W2, W2_t, 4096, 1024);
    concat_bias<<<12, 256, 0, stream>>>(bq, bk, bv, bqkv);
    ln_bf16<<<8192, 256, 0, stream>>>(x, ln1_g, ln1_b, hbuf);
    gemm_bf16<<<dim3(24, 64), 256, 0, stream>>>(hbuf, Wqkv_t, 8192, 3072, 1024,
                                                bqkv, nullptr, nullptr, qkv, 0);
    transpose_v<<<dim3(64, 2, 64), 256, 0, stream>>>(qkv, Vt);
    attn_kernel<<<dim3(8, 16, 4), 256, 0, stream>>>(qkv, Vt, ctx);
    gemm_bf16<<<dim3(8, 64), 256, 0, stream>>>(ctx, Wo_t, 8192, 1024, 1024,
                                               bo, x, x2, nullptr, 1);
    ln_bf16<<<8192, 256, 0, stream>>>(x2, ln2_g, ln2_b, h2);
    gemm_bf16<<<dim3(32, 64), 256, 0, stream>>>(h2, W1_t, 8192, 4096, 1024,
                                                b1, nullptr, nullptr, a1, 2);
    gemm_bf16<<<dim3(8, 64), 256, 0, stream>>>(a1, W2_t, 8192, 1024, 4096,
                                               b2, x2, out, nullptr, 1);
}

// Round 5
// 567.644 us; speedup vs baseline: 1.7678x; 1.0241x over previous
//
#include <hip/hip_runtime.h>
#include <cstdint>
#include <cstddef>

// ---------------------------------------------------------------------------
// Types / helpers
// ---------------------------------------------------------------------------
typedef __bf16 bf16x8 __attribute__((ext_vector_type(8)));
typedef float  floatx4 __attribute__((ext_vector_type(4)));

__device__ __forceinline__ uint16_t f2b(float f) {
    uint32_t u = __builtin_bit_cast(uint32_t, f);
    return (uint16_t)((u + 0x7fffu + ((u >> 16) & 1)) >> 16);  // RNE
}

__device__ __forceinline__ uint16_t bf16bits(float f) {       // HW v_cvt (RNE)
    __bf16 h = (__bf16)f;
    return __builtin_bit_cast(uint16_t, h);
}

__device__ __forceinline__ void gload_lds16(const void* g, void* l) {
    __builtin_amdgcn_global_load_lds(
        (__attribute__((address_space(1))) void*)(void*)g,
        (__attribute__((address_space(3))) void*)l, 16, 0, 0);
}

// DPP row_ror helpers: 16-lane-row reductions entirely in the VALU pipe.
template<int CTRL>
__device__ __forceinline__ float dpp_rot(float v) {
    return __builtin_bit_cast(float,
        __builtin_amdgcn_update_dpp(0, __builtin_bit_cast(int, v),
                                    CTRL, 0xf, 0xf, true));
}
__device__ __forceinline__ float rowmax16(float v) {
    v = fmaxf(v, dpp_rot<0x128>(v));
    v = fmaxf(v, dpp_rot<0x124>(v));
    v = fmaxf(v, dpp_rot<0x122>(v));
    v = fmaxf(v, dpp_rot<0x121>(v));
    return v;
}
__device__ __forceinline__ float rowsum16(float v) {
    v += dpp_rot<0x128>(v);
    v += dpp_rot<0x124>(v);
    v += dpp_rot<0x122>(v);
    v += dpp_rot<0x121>(v);
    return v;
}

// 0.125 (1/sqrt(HD)) * log2(e): folded into Wq/bq so softmax is exp2-domain.
#define QSCALE 0.18033688011112042f

// ---------------------------------------------------------------------------
// Weight repack kernels (fp32 -> bf16, transposed to [N][K])
// ---------------------------------------------------------------------------
__global__ __launch_bounds__(256) void repack_qkv(
    const float* __restrict__ Wq, const float* __restrict__ Wk,
    const float* __restrict__ Wv, uint16_t* __restrict__ out)
{
    __shared__ uint16_t tile[32][33];
    const int m = blockIdx.z >> 4, h = blockIdx.z & 15;
    const float* W = (m == 0) ? Wq : (m == 1) ? Wk : Wv;
    const float scl = (m == 0) ? QSCALE : 1.0f;
    const float* src = W + (size_t)h * 1024 * 64;           // [1024][64]
    const int d0 = blockIdx.x * 32, hd0 = blockIdx.y * 32;
    const int tx = threadIdx.x & 31, ty = threadIdx.x >> 5;
#pragma unroll
    for (int i = 0; i < 4; ++i)
        tile[ty + i * 8][tx] = f2b(src[(size_t)(d0 + ty + i * 8) * 64 + hd0 + tx] * scl);
    __syncthreads();
    uint16_t* dst = out + (size_t)(m * 1024 + h * 64) * 1024; // [64][1024]
#pragma unroll
    for (int i = 0; i < 4; ++i)
        dst[(size_t)(hd0 + ty + i * 8) * 1024 + d0 + tx] = tile[tx][ty + i * 8];
}

__global__ __launch_bounds__(256) void transpose_f2b(
    const float* __restrict__ in, uint16_t* __restrict__ out, int R, int C)
{
    __shared__ uint16_t tile[32][33];
    const int c0 = blockIdx.x * 32, r0 = blockIdx.y * 32;
    const int tx = threadIdx.x & 31, ty = threadIdx.x >> 5;
#pragma unroll
    for (int i = 0; i < 4; ++i)
        tile[ty + i * 8][tx] = f2b(in[(size_t)(r0 + ty + i * 8) * C + c0 + tx]);
    __syncthreads();
#pragma unroll
    for (int i = 0; i < 4; ++i)
        out[(size_t)(c0 + ty + i * 8) * R + r0 + tx] = tile[tx][ty + i * 8];
}

__global__ void concat_bias(const float* __restrict__ bq, const float* __restrict__ bk,
                            const float* __restrict__ bv, float* __restrict__ out)
{
    int i = blockIdx.x * 256 + threadIdx.x;  // 3072 total
    out[i] = (i < 1024) ? bq[i] * QSCALE : (i < 2048) ? bk[i - 1024] : bv[i - 2048];
}

// V slice of qkv [B*T][3072] (cols 2048+h*64+hd) -> Vt [(b*16+h)*64+hd][2048]
__global__ __launch_bounds__(256) void transpose_v(
    const uint16_t* __restrict__ qkv, uint16_t* __restrict__ Vt)
{
    __shared__ uint16_t tile[32][33];
    const int bh = blockIdx.z;
    const int b = bh >> 4, h = bh & 15;
    const int t0 = blockIdx.x * 32, hd0 = blockIdx.y * 32;
    const int tx = threadIdx.x & 31, ty = threadIdx.x >> 5;
    const uint16_t* src = qkv + (size_t)b * 2048 * 3072 + 2048 + h * 64;
#pragma unroll
    for (int i = 0; i < 4; ++i)
        tile[ty + i * 8][tx] = src[(size_t)(t0 + ty + i * 8) * 3072 + hd0 + tx];
    __syncthreads();
    uint16_t* dst = Vt + (size_t)bh * 64 * 2048;
#pragma unroll
    for (int i = 0; i < 4; ++i)
        dst[(size_t)(hd0 + ty + i * 8) * 2048 + t0 + tx] = tile[tx][ty + i * 8];
}

// ---------------------------------------------------------------------------
// LayerNorm: fp32 [rows][1024] -> bf16, one block per row
// ---------------------------------------------------------------------------
__global__ __launch_bounds__(256) void ln_bf16(
    const float* __restrict__ x, const float* __restrict__ g,
    const float* __restrict__ b, uint16_t* __restrict__ out)
{
    const int row = blockIdx.x;
    const int t = threadIdx.x;
    const float4 v = ((const float4*)(x + (size_t)row * 1024))[t];
    float s  = v.x + v.y + v.z + v.w;
    float s2 = v.x * v.x + v.y * v.y + v.z * v.z + v.w * v.w;
#pragma unroll
    for (int o = 32; o > 0; o >>= 1) { s += __shfl_down(s, o); s2 += __shfl_down(s2, o); }
    __shared__ float red[8];
    const int wave = t >> 6, lane = t & 63;
    if (lane == 0) { red[wave] = s; red[4 + wave] = s2; }
    __syncthreads();
    if (t == 0) {
        float a  = red[0] + red[1] + red[2] + red[3];
        float a2 = red[4] + red[5] + red[6] + red[7];
        float mu = a * (1.0f / 1024.0f);
        red[0] = mu;
        red[4] = rsqrtf(a2 * (1.0f / 1024.0f) - mu * mu + 1e-5f);
    }
    __syncthreads();
    const float mu = red[0], rs = red[4];
    const float4 gv = ((const float4*)g)[t];
    const float4 bv = ((const float4*)b)[t];
    ushort4 ov;
    ov.x = f2b((v.x - mu) * rs * gv.x + bv.x);
    ov.y = f2b((v.y - mu) * rs * gv.y + bv.y);
    ov.z = f2b((v.z - mu) * rs * gv.z + bv.z);
    ov.w = f2b((v.w - mu) * rs * gv.w + bv.w);
    ((ushort4*)(out + (size_t)row * 1024))[t] = ov;
}

// ---------------------------------------------------------------------------
// GEMM: C[M,N] = A[M,K](bf16,rowmajor) * Bt[N,K](bf16,rowmajor)^T + bias
// mode 0: out bf16            mode 1: out fp32 + resid      mode 2: bf16 gelu
// 128x128x32 tiles. XCD-aware mapping: wg->XCD is (lid % 8) round-robin, so
// lid = 8*t + xcd; each XCD owns a band of 8 tile-rows (2MB A-slice) and
// walks it in 8-tile-column chunks (2MB B-slice) -> ~4MB/XCD L2 working set.
// K-loop LDS XOR-swizzled (slot = chunk ^ ((row>>1)&3)): 2-way max on b128
// reads. Epilogue staged through LDS for full-line stores.
// Requires: M % 1024 == 0, N % 1024 == 0 (all call sites comply).
// ---------------------------------------------------------------------------
__global__ __launch_bounds__(256, 2) void gemm_bf16(
    const uint16_t* __restrict__ A, const uint16_t* __restrict__ Bt,
    int M, int N, int K,
    const float* __restrict__ bias, const float* __restrict__ resid,
    float* __restrict__ outF, uint16_t* __restrict__ outB, int mode)
{
    __shared__ __align__(16) uint16_t lds[128 * 128];   // 32KB: staging + epilogue
    uint16_t* lA = lds;                                  // 128*32 (8KB)
    uint16_t* lB = lds + 128 * 32;                       // 8KB
    const int tid  = threadIdx.x;
    const int wave = tid >> 6, lane = tid & 63;

    // XCD-aware tile mapping
    const int lid = (int)blockIdx.y * (int)gridDim.x + (int)blockIdx.x;
    const int xcd = lid & 7, t = lid >> 3;
    const int Mb = (M >> 7) >> 3;          // tile-rows per XCD band (pow2)
    const int perChunk = Mb * 8;
    const int ch = t / perChunk, j = t - ch * perChunk;
    const int m0 = (xcd * Mb + (j & (Mb - 1))) * 128;
    const int n0 = (ch * 8 + (j / Mb)) * 128;

    const int wm = (wave >> 1) * 64, wn = (wave & 1) * 64;
    const int lrow = lane & 15;
    const int wbase = wave * 64;
    // swizzled k-chunk slot for fragment reads (2-way max bank aliasing)
    const int lkSw = (((lane >> 4) ^ ((lrow >> 1) & 3))) * 8;

    floatx4 acc[4][4] = {};

    const uint16_t* aT = A  + (size_t)m0 * K;
    const uint16_t* bT = Bt + (size_t)n0 * K;

    for (int k0 = 0; k0 < K; k0 += 32) {
        __syncthreads();
#pragma unroll
        for (int i = 0; i < 2; ++i) {
            const int cw = i * 256 + wbase;      // wave-uniform chunk base
            const int q  = cw + lane;            // LDS slot chunk id
            const int row = q >> 2;
            const int kc = ((q & 3) ^ ((row >> 1) & 3)) * 8;   // swizzled fetch
            gload_lds16(aT + (size_t)row * K + k0 + kc, &lA[cw * 8]);
            gload_lds16(bT + (size_t)row * K + k0 + kc, &lB[cw * 8]);
        }
        __syncthreads();
        bf16x8 af[4], bfr[4];
#pragma unroll
        for (int mi = 0; mi < 4; ++mi)
            af[mi] = *(const bf16x8*)&lA[(wm + mi * 16 + lrow) * 32 + lkSw];
#pragma unroll
        for (int ni = 0; ni < 4; ++ni)
            bfr[ni] = *(const bf16x8*)&lB[(wn + ni * 16 + lrow) * 32 + lkSw];
#pragma unroll
        for (int mi = 0; mi < 4; ++mi)
#pragma unroll
            for (int ni = 0; ni < 4; ++ni)
                acc[mi][ni] = __builtin_amdgcn_mfma_f32_16x16x32_bf16(
                    af[mi], bfr[ni], acc[mi][ni], 0, 0, 0);
    }

    __syncthreads();                           // staging buffers free now
    const int r0 = (lane >> 4) * 4;

    if (mode == 1) {
        // fp32 + residual, two 64-row passes staged in LDS (32KB fp32)
        float* cf = (float*)lds;
#pragma unroll
        for (int p = 0; p < 2; ++p) {
            if ((wave >> 1) == p) {
#pragma unroll
                for (int ni = 0; ni < 4; ++ni) {
                    const int col = wn + ni * 16 + lrow;
                    const float bv = bias[n0 + col];
#pragma unroll
                    for (int mi = 0; mi < 4; ++mi)
#pragma unroll
                        for (int r = 0; r < 4; ++r) {
                            const int row = mi * 16 + r0 + r;       // 0..63
                            const int g = (col >> 2) ^ (((row >> 2) & 1) << 2);
                            cf[row * 128 + g * 4 + (col & 3)] = acc[mi][ni][r] + bv;
                        }
                }
            }
            __syncthreads();
#pragma unroll
            for (int i = 0; i < 8; ++i) {
                const int ci = i * 256 + tid;        // 16B chunk id
                const int row = ci >> 5, cg = ci & 31;
                const int g = cg ^ (((row >> 2) & 1) << 2);
                float4 v = *(const float4*)&cf[row * 128 + g * 4];
                const size_t gidx = (size_t)(m0 + p * 64 + row) * N + n0 + cg * 4;
                const float4 rz = *(const float4*)&resid[gidx];
                v.x += rz.x; v.y += rz.y; v.z += rz.z; v.w += rz.w;
                *(float4*)&outF[gidx] = v;
            }
            __syncthreads();
        }
    } else {
        // bf16 out (mode 0 plain / mode 2 gelu), full 128x128 tile in LDS
#pragma unroll
        for (int ni = 0; ni < 4; ++ni) {
            const int col = wn + ni * 16 + lrow;
            const float bv = bias[n0 + col];
#pragma unroll
            for (int mi = 0; mi < 4; ++mi)
#pragma unroll
                for (int r = 0; r < 4; ++r) {
                    const int row = wm + mi * 16 + r0 + r;
                    float v = acc[mi][ni][r] + bv;
                    if (mode == 2)
                        v = 0.5f * v * (1.0f + erff(v * 0.70710678118654752f));
                    const int g = (col >> 3) ^ (((row >> 2) & 3) << 1);
                    lds[row * 128 + g * 8 + (col & 7)] = bf16bits(v);
                }
        }
        __syncthreads();
#pragma unroll
        for (int i = 0; i < 8; ++i) {
            const int ci = i * 256 + tid;            // 16B chunk id
            const int row = ci >> 4, cg = ci & 15;
            const int g = cg ^ (((row >> 2) & 3) << 1);
            const bf16x8 v = *(const bf16x8*)&lds[row * 128 + g * 8];
            *(bf16x8*)&outB[(size_t)(m0 + row) * N + n0 + cg * 8] = v;
        }
    }
}

// ---------------------------------------------------------------------------
// Flash attention v4 (causal, balanced, 2 blocks/CU).
// Grid (8, 16, 4) = 512 blocks; block x does q-tiles (15-x) then (x), 128
// rows each -> uniform 34 K-tiles/block. 4 waves; wave owns 32 q-rows.
// K/V 64x64 tiles staged via global_load_lds, double-buffered, XOR-swizzled.
// Softmax natively exp2-domain (scale folded into Wq/bq); DPP reductions.
// ---------------------------------------------------------------------------
__global__ __launch_bounds__(256, 2) void attn_kernel(
    const uint16_t* __restrict__ qkv, const uint16_t* __restrict__ Vt,
    uint16_t* __restrict__ ctx)
{
    const int h = blockIdx.y, b = blockIdx.z;
    const int tid = threadIdx.x, wave = tid >> 6, lane = tid & 63;
    const int quad = lane >> 4, lcol = lane & 15, lr4 = quad * 4;
    const int sx = lcol & 7;
    const uint16_t* qbase = qkv + (size_t)b * 2048 * 3072;
    const uint16_t* kgb = qbase + 1024 + h * 64;
    const uint16_t* vtb = Vt + (size_t)(b * 16 + h) * 64 * 2048;

    __shared__ __align__(16) uint16_t kbuf[2][64 * 64];
    __shared__ __align__(16) uint16_t vbuf[2][64 * 64];
    __shared__ __align__(16) uint16_t pshm[4][32 * 64];

    const int rr = lane >> 3, sl = lane & 7;
    const int swz = sl ^ rr;                 // global 16B-chunk this lane fetches

#define STAGE(ktile, bb)                                                        \
    {                                                                           \
        const int _kb = (ktile) * 64;                                           \
        _Pragma("unroll")                                                       \
        for (int i = 0; i < 2; ++i) {                                           \
            const int j = wave * 2 + i;                                         \
            const int r = j * 8 + rr;                                           \
            gload_lds16(kgb + (size_t)(_kb + r) * 3072 + swz * 8,               \
                        &kbuf[bb][j * 512]);                                    \
            gload_lds16(vtb + (size_t)r * 2048 + _kb + swz * 8,                 \
                        &vbuf[bb][j * 512]);                                    \
        }                                                                       \
    }

    for (int pp = 0; pp < 2; ++pp) {
        const int qt = pp ? (int)blockIdx.x : 15 - (int)blockIdx.x;
        const int qr0 = qt * 128 + wave * 32;

        // Q fragments (A-layout): m = lcol, k = quad*8+j (+32 second chunk)
        bf16x8 qf[2][2];
#pragma unroll
        for (int mi = 0; mi < 2; ++mi) {
            const uint16_t* qp = qbase + (size_t)(qr0 + mi * 16 + lcol) * 3072 + h * 64;
            qf[mi][0] = *(const bf16x8*)(qp + quad * 8);
            qf[mi][1] = *(const bf16x8*)(qp + 32 + quad * 8);
        }

        floatx4 o[2][4] = {};
        float m_i[2][4], l_i[2][4];
#pragma unroll
        for (int mi = 0; mi < 2; ++mi)
#pragma unroll
            for (int r = 0; r < 4; ++r) { m_i[mi][r] = -1e30f; l_i[mi][r] = 0.f; }

        const int nk = 2 * qt + 2;
        __syncthreads();                       // prior pass done with buffers
        STAGE(0, 0);
        int cur = 0;

        for (int kt = 0; kt < nk; ++kt) {
            const int kb = kt * 64;
            __syncthreads();                   // drains vmcnt: buf[cur] ready
            if (kt + 1 < nk) STAGE(kt + 1, cur ^ 1);

            if (kb <= qr0 + 31) {              // wave-uniform causal skip
                bf16x8 kf[4][2];
#pragma unroll
                for (int nt = 0; nt < 4; ++nt) {
                    const int krow = nt * 16 + lcol;
                    kf[nt][0] = *(const bf16x8*)&kbuf[cur][krow * 64 + ((quad ^ sx) * 8)];
                    kf[nt][1] = *(const bf16x8*)&kbuf[cur][krow * 64 + (((quad + 4) ^ sx) * 8)];
                }
#pragma unroll
                for (int mi = 0; mi < 2; ++mi) {
                    floatx4 sv[4];
#pragma unroll
                    for (int nt = 0; nt < 4; ++nt) {
                        floatx4 s = {0.f, 0.f, 0.f, 0.f};
                        s = __builtin_amdgcn_mfma_f32_16x16x32_bf16(qf[mi][0], kf[nt][0], s, 0, 0, 0);
                        s = __builtin_amdgcn_mfma_f32_16x16x32_bf16(qf[mi][1], kf[nt][1], s, 0, 0, 0);
                        sv[nt] = s;
                    }
                    if (kb + 63 > qr0 + mi * 16) {     // causal mask needed
#pragma unroll
                        for (int nt = 0; nt < 4; ++nt)
#pragma unroll
                            for (int r = 0; r < 4; ++r) {
                                const int row = qr0 + mi * 16 + lr4 + r;
                                const int col = kb + nt * 16 + lcol;
                                if (col > row) sv[nt][r] = -1e30f;
                            }
                    }
#pragma unroll
                    for (int r = 0; r < 4; ++r) {
                        float m = fmaxf(fmaxf(sv[0][r], sv[1][r]),
                                        fmaxf(sv[2][r], sv[3][r]));
                        m = rowmax16(m);
                        const float mn = fmaxf(m_i[mi][r], m);
                        const float alpha = __builtin_amdgcn_exp2f(m_i[mi][r] - mn);
                        m_i[mi][r] = mn;
                        const int row = mi * 16 + lr4 + r;
                        const int rsw = row & 7;
                        float l = 0.f;
#pragma unroll
                        for (int nt = 0; nt < 4; ++nt) {
                            const float p = __builtin_amdgcn_exp2f(sv[nt][r] - mn);
                            l += p;
                            const int col = nt * 16 + lcol;
                            pshm[wave][row * 64 + (((col >> 3) ^ rsw) * 8) + (col & 7)] =
                                bf16bits(p);
                        }
                        l = rowsum16(l);
                        l_i[mi][r] = l_i[mi][r] * alpha + l;
#pragma unroll
                        for (int ht = 0; ht < 4; ++ht) o[mi][ht][r] *= alpha;
                    }
                }
                // P (A-layout) fragments from pshm
                bf16x8 pf[2][2];
#pragma unroll
                for (int mi = 0; mi < 2; ++mi) {
                    const int prow = mi * 16 + lcol;
                    pf[mi][0] = *(const bf16x8*)&pshm[wave][prow * 64 + ((quad ^ sx) * 8)];
                    pf[mi][1] = *(const bf16x8*)&pshm[wave][prow * 64 + (((quad + 4) ^ sx) * 8)];
                }
#pragma unroll
                for (int ht = 0; ht < 4; ++ht) {
                    const int hd = ht * 16 + lcol;
                    const bf16x8 vf0 = *(const bf16x8*)&vbuf[cur][hd * 64 + ((quad ^ sx) * 8)];
                    const bf16x8 vf1 = *(const bf16x8*)&vbuf[cur][hd * 64 + (((quad + 4) ^ sx) * 8)];
#pragma unroll
                    for (int mi = 0; mi < 2; ++mi) {
                        o[mi][ht] = __builtin_amdgcn_mfma_f32_16x16x32_bf16(pf[mi][0], vf0, o[mi][ht], 0, 0, 0);
                        o[mi][ht] = __builtin_amdgcn_mfma_f32_16x16x32_bf16(pf[mi][1], vf1, o[mi][ht], 0, 0, 0);
                    }
                }
            }
            cur ^= 1;
        }

#pragma unroll
        for (int mi = 0; mi < 2; ++mi)
#pragma unroll
            for (int r = 0; r < 4; ++r) {
                const float inv = 1.0f / l_i[mi][r];
                const int row = qr0 + mi * 16 + lr4 + r;
#pragma unroll
                for (int ht = 0; ht < 4; ++ht)
                    ctx[(size_t)(b * 2048 + row) * 1024 + h * 64 + ht * 16 + lcol] =
                        bf16bits(o[mi][ht][r] * inv);
            }
    }
#undef STAGE
}

// ---------------------------------------------------------------------------
// Launch
// ---------------------------------------------------------------------------
extern "C" void kernel_launch(void* const* d_in, const int* in_sizes, int n_in,
                              void* d_out, int out_size, void* d_ws, size_t ws_size,
                              hipStream_t stream)
{
    (void)in_sizes; (void)n_in; (void)out_size; (void)ws_size;
    const float* x     = (const float*)d_in[0];
    const float* ln1_g = (const float*)d_in[2];
    const float* ln1_b = (const float*)d_in[3];
    const float* Wq    = (const float*)d_in[4];
    const float* bq    = (const float*)d_in[5];
    const float* Wk    = (const float*)d_in[6];
    const float* bk    = (const float*)d_in[7];
    const float* Wv    = (const float*)d_in[8];
    const float* bv    = (const float*)d_in[9];
    const float* Wo    = (const float*)d_in[10];
    const float* bo    = (const float*)d_in[11];
    const float* ln2_g = (const float*)d_in[12];
    const float* ln2_b = (const float*)d_in[13];
    const float* W1    = (const float*)d_in[14];
    const float* b1    = (const float*)d_in[15];
    const float* W2    = (const float*)d_in[16];
    const float* b2    = (const float*)d_in[17];
    float* out = (float*)d_out;

    char* w = (char*)d_ws;
    uint16_t* Wqkv_t = (uint16_t*)w;  w += 6291456;    // [3072][1024]
    uint16_t* Wo_t   = (uint16_t*)w;  w += 2097152;    // [1024][1024]
    uint16_t* W1_t   = (uint16_t*)w;  w += 8388608;    // [4096][1024]
    uint16_t* W2_t   = (uint16_t*)w;  w += 8388608;    // [1024][4096]
    float*    bqkv   = (float*)w;     w += 16384;      // [3072]
    float*    x2     = (float*)w;     w += 33554432;   // [8192][1024] fp32
    char* region = w;
    uint16_t* hbuf = (uint16_t*)region;                        // 16MB h, later ctx
    uint16_t* qkv  = (uint16_t*)(region + 16777216);           // 48MB
    uint16_t* Vt   = (uint16_t*)(region + 16777216 + 50331648);// 16MB
    uint16_t* ctx  = hbuf;
    uint16_t* h2   = (uint16_t*)region;
    uint16_t* a1   = (uint16_t*)(region + 16777216);

    repack_qkv<<<dim3(32, 2, 48), 256, 0, stream>>>(Wq, Wk, Wv, Wqkv_t);
    transpose_f2b<<<dim3(32, 32),  256, 0, stream>>>(Wo, Wo_t, 1024, 1024);
    transpose_f2b<<<dim3(128, 32), 256, 0, stream>>>(W1, W1_t, 1024, 4096);
    transpose_f2b<<<dim3(32, 128), 256, 0, stream>>>(W2, W2_t, 4096, 1024);
    concat_bias<<<12, 256, 0, stream>>>(bq, bk, bv, bqkv);
    ln_bf16<<<8192, 256, 0, stream>>>(x, ln1_g, ln1_b, hbuf);
    gemm_bf16<<<dim3(24, 64), 256, 0, stream>>>(hbuf, Wqkv_t, 8192, 3072, 1024,
                                                bqkv, nullptr, nullptr, qkv, 0);
    transpose_v<<<dim3(64, 2, 64), 256, 0, stream>>>(qkv, Vt);
    attn_kernel<<<dim3(8, 16, 4), 256, 0, stream>>>(qkv, Vt, ctx);
    gemm_bf16<<<dim3(8, 64), 256, 0, stream>>>(ctx, Wo_t, 8192, 1024, 1024,
                                               bo, x, x2, nullptr, 1);
    ln_bf16<<<8192, 256, 0, stream>>>(x2, ln2_g, ln2_b, h2);
    gemm_bf16<<<dim3(32, 64), 256, 0, stream>>>(h2, W1_t, 8192, 4096, 1024,
                                                b1, nullptr, nullptr, a1, 2);
    gemm_bf16<<<dim3(8, 64), 256, 0, stream>>>(a1, W2_t, 8192, 1024, 4096,
                                               b2, x2, out, nullptr, 1);
}

// Round 6
// 501.598 us; speedup vs baseline: 2.0005x; 1.1317x over previous
//
#include <hip/hip_runtime.h>
#include <cstdint>
#include <cstddef>

// ---------------------------------------------------------------------------
// Types / helpers
// ---------------------------------------------------------------------------
typedef __bf16 bf16x8 __attribute__((ext_vector_type(8)));
typedef float  floatx4 __attribute__((ext_vector_type(4)));

__device__ __forceinline__ uint16_t f2b(float f) {
    uint32_t u = __builtin_bit_cast(uint32_t, f);
    return (uint16_t)((u + 0x7fffu + ((u >> 16) & 1)) >> 16);  // RNE
}

__device__ __forceinline__ uint16_t bf16bits(float f) {       // HW v_cvt (RNE)
    __bf16 h = (__bf16)f;
    return __builtin_bit_cast(uint16_t, h);
}

__device__ __forceinline__ void gload_lds16(const void* g, void* l) {
    __builtin_amdgcn_global_load_lds(
        (__attribute__((address_space(1))) void*)(void*)g,
        (__attribute__((address_space(3))) void*)l, 16, 0, 0);
}

// DPP row_ror helpers: 16-lane-row reductions entirely in the VALU pipe.
template<int CTRL>
__device__ __forceinline__ float dpp_rot(float v) {
    return __builtin_bit_cast(float,
        __builtin_amdgcn_update_dpp(0, __builtin_bit_cast(int, v),
                                    CTRL, 0xf, 0xf, true));
}
__device__ __forceinline__ float rowmax16(float v) {
    v = fmaxf(v, dpp_rot<0x128>(v));
    v = fmaxf(v, dpp_rot<0x124>(v));
    v = fmaxf(v, dpp_rot<0x122>(v));
    v = fmaxf(v, dpp_rot<0x121>(v));
    return v;
}
__device__ __forceinline__ float rowsum16(float v) {
    v += dpp_rot<0x128>(v);
    v += dpp_rot<0x124>(v);
    v += dpp_rot<0x122>(v);
    v += dpp_rot<0x121>(v);
    return v;
}

// 0.125 (1/sqrt(HD)) * log2(e): folded into Wq/bq so softmax is exp2-domain.
#define QSCALE 0.18033688011112042f

// ---------------------------------------------------------------------------
// Weight repack kernels (fp32 -> bf16, transposed to [N][K])
// ---------------------------------------------------------------------------
__global__ __launch_bounds__(256) void repack_qkv(
    const float* __restrict__ Wq, const float* __restrict__ Wk,
    const float* __restrict__ Wv, uint16_t* __restrict__ out)
{
    __shared__ uint16_t tile[32][33];
    const int m = blockIdx.z >> 4, h = blockIdx.z & 15;
    const float* W = (m == 0) ? Wq : (m == 1) ? Wk : Wv;
    const float scl = (m == 0) ? QSCALE : 1.0f;
    const float* src = W + (size_t)h * 1024 * 64;           // [1024][64]
    const int d0 = blockIdx.x * 32, hd0 = blockIdx.y * 32;
    const int tx = threadIdx.x & 31, ty = threadIdx.x >> 5;
#pragma unroll
    for (int i = 0; i < 4; ++i)
        tile[ty + i * 8][tx] = f2b(src[(size_t)(d0 + ty + i * 8) * 64 + hd0 + tx] * scl);
    __syncthreads();
    uint16_t* dst = out + (size_t)(m * 1024 + h * 64) * 1024; // [64][1024]
#pragma unroll
    for (int i = 0; i < 4; ++i)
        dst[(size_t)(hd0 + ty + i * 8) * 1024 + d0 + tx] = tile[tx][ty + i * 8];
}

__global__ __launch_bounds__(256) void transpose_f2b(
    const float* __restrict__ in, uint16_t* __restrict__ out, int R, int C)
{
    __shared__ uint16_t tile[32][33];
    const int c0 = blockIdx.x * 32, r0 = blockIdx.y * 32;
    const int tx = threadIdx.x & 31, ty = threadIdx.x >> 5;
#pragma unroll
    for (int i = 0; i < 4; ++i)
        tile[ty + i * 8][tx] = f2b(in[(size_t)(r0 + ty + i * 8) * C + c0 + tx]);
    __syncthreads();
#pragma unroll
    for (int i = 0; i < 4; ++i)
        out[(size_t)(c0 + ty + i * 8) * R + r0 + tx] = tile[tx][ty + i * 8];
}

__global__ void concat_bias(const float* __restrict__ bq, const float* __restrict__ bk,
                            const float* __restrict__ bv, float* __restrict__ out)
{
    int i = blockIdx.x * 256 + threadIdx.x;  // 3072 total
    out[i] = (i < 1024) ? bq[i] * QSCALE : (i < 2048) ? bk[i - 1024] : bv[i - 2048];
}

// V slice of qkv [B*T][3072] (cols 2048+h*64+hd) -> Vt [(b*16+h)*64+hd][2048]
__global__ __launch_bounds__(256) void transpose_v(
    const uint16_t* __restrict__ qkv, uint16_t* __restrict__ Vt)
{
    __shared__ uint16_t tile[32][33];
    const int bh = blockIdx.z;
    const int b = bh >> 4, h = bh & 15;
    const int t0 = blockIdx.x * 32, hd0 = blockIdx.y * 32;
    const int tx = threadIdx.x & 31, ty = threadIdx.x >> 5;
    const uint16_t* src = qkv + (size_t)b * 2048 * 3072 + 2048 + h * 64;
#pragma unroll
    for (int i = 0; i < 4; ++i)
        tile[ty + i * 8][tx] = src[(size_t)(t0 + ty + i * 8) * 3072 + hd0 + tx];
    __syncthreads();
    uint16_t* dst = Vt + (size_t)bh * 64 * 2048;
#pragma unroll
    for (int i = 0; i < 4; ++i)
        dst[(size_t)(hd0 + ty + i * 8) * 2048 + t0 + tx] = tile[tx][ty + i * 8];
}

// ---------------------------------------------------------------------------
// LayerNorm: fp32 [rows][1024] -> bf16, one block per row
// ---------------------------------------------------------------------------
__global__ __launch_bounds__(256) void ln_bf16(
    const float* __restrict__ x, const float* __restrict__ g,
    const float* __restrict__ b, uint16_t* __restrict__ out)
{
    const int row = blockIdx.x;
    const int t = threadIdx.x;
    const float4 v = ((const float4*)(x + (size_t)row * 1024))[t];
    float s  = v.x + v.y + v.z + v.w;
    float s2 = v.x * v.x + v.y * v.y + v.z * v.z + v.w * v.w;
#pragma unroll
    for (int o = 32; o > 0; o >>= 1) { s += __shfl_down(s, o); s2 += __shfl_down(s2, o); }
    __shared__ float red[8];
    const int wave = t >> 6, lane = t & 63;
    if (lane == 0) { red[wave] = s; red[4 + wave] = s2; }
    __syncthreads();
    if (t == 0) {
        float a  = red[0] + red[1] + red[2] + red[3];
        float a2 = red[4] + red[5] + red[6] + red[7];
        float mu = a * (1.0f / 1024.0f);
        red[0] = mu;
        red[4] = rsqrtf(a2 * (1.0f / 1024.0f) - mu * mu + 1e-5f);
    }
    __syncthreads();
    const float mu = red[0], rs = red[4];
    const float4 gv = ((const float4*)g)[t];
    const float4 bv = ((const float4*)b)[t];
    ushort4 ov;
    ov.x = f2b((v.x - mu) * rs * gv.x + bv.x);
    ov.y = f2b((v.y - mu) * rs * gv.y + bv.y);
    ov.z = f2b((v.z - mu) * rs * gv.z + bv.z);
    ov.w = f2b((v.w - mu) * rs * gv.w + bv.w);
    ((ushort4*)(out + (size_t)row * 1024))[t] = ov;
}

// ---------------------------------------------------------------------------
// GEMM: C[M,N] = A[M,K](bf16,rowmajor) * Bt[N,K](bf16,rowmajor)^T + bias
// mode 0: out bf16            mode 1: out fp32 + resid      mode 2: bf16 gelu
// 128x128 tile, BK=64 (half the barriers of BK=32; 32 MFMA per drain).
// XCD-aware mapping: lid = 8*t + xcd; each XCD owns a band of 8 tile-rows
// (2MB A) walked in 8-tile-column chunks (2MB B) -> ~4MB/XCD L2 working set.
// LDS full 8-slot XOR swizzle (slot = chunk ^ (row&7)): conflict-free b128.
// 3 blocks/CU (launch_bounds min-waves=3) for cross-block barrier overlap.
// Requires: M % 1024 == 0, N % 1024 == 0, K % 64 == 0.
// ---------------------------------------------------------------------------
__global__ __launch_bounds__(256, 3) void gemm_bf16(
    const uint16_t* __restrict__ A, const uint16_t* __restrict__ Bt,
    int M, int N, int K,
    const float* __restrict__ bias, const float* __restrict__ resid,
    float* __restrict__ outF, uint16_t* __restrict__ outB, int mode)
{
    __shared__ __align__(16) uint16_t lds[128 * 128];   // 32KB: staging + epilogue
    uint16_t* lA = lds;                                  // 128x64 (16KB)
    uint16_t* lB = lds + 128 * 64;                       // 16KB
    const int tid  = threadIdx.x;
    const int wave = tid >> 6, lane = tid & 63;

    // XCD-aware tile mapping
    const int lid = (int)blockIdx.y * (int)gridDim.x + (int)blockIdx.x;
    const int xcd = lid & 7, t = lid >> 3;
    const int Mb = (M >> 7) >> 3;          // tile-rows per XCD band (pow2)
    const int perChunk = Mb * 8;
    const int ch = t / perChunk, j = t - ch * perChunk;
    const int m0 = (xcd * Mb + (j & (Mb - 1))) * 128;
    const int n0 = (ch * 8 + (j / Mb)) * 128;

    const int wm = (wave >> 1) * 64, wn = (wave & 1) * 64;
    const int quad = lane >> 4, lrow = lane & 15;
    const int wbase = wave * 64;

    floatx4 acc[4][4] = {};

    const uint16_t* aT = A  + (size_t)m0 * K;
    const uint16_t* bT = Bt + (size_t)n0 * K;

    for (int k0 = 0; k0 < K; k0 += 64) {
        __syncthreads();
#pragma unroll
        for (int i = 0; i < 4; ++i) {
            const int cw = i * 256 + wbase;      // wave-uniform chunk base
            const int q  = cw + lane;            // LDS slot chunk id (0..1023)
            const int row = q >> 3;
            const int g = ((q & 7) ^ (row & 7)) * 8;   // swizzled global chunk
            gload_lds16(aT + (size_t)row * K + k0 + g, &lA[cw * 8]);
            gload_lds16(bT + (size_t)row * K + k0 + g, &lB[cw * 8]);
        }
        __syncthreads();
        bf16x8 af[4][2], bfr[4][2];
#pragma unroll
        for (int mi = 0; mi < 4; ++mi) {
            const int rr = wm + mi * 16 + lrow;
#pragma unroll
            for (int hh = 0; hh < 2; ++hh)
                af[mi][hh] = *(const bf16x8*)
                    &lA[rr * 64 + (((hh * 4 + quad) ^ (rr & 7)) * 8)];
        }
#pragma unroll
        for (int ni = 0; ni < 4; ++ni) {
            const int rr = wn + ni * 16 + lrow;
#pragma unroll
            for (int hh = 0; hh < 2; ++hh)
                bfr[ni][hh] = *(const bf16x8*)
                    &lB[rr * 64 + (((hh * 4 + quad) ^ (rr & 7)) * 8)];
        }
#pragma unroll
        for (int mi = 0; mi < 4; ++mi)
#pragma unroll
            for (int ni = 0; ni < 4; ++ni) {
                acc[mi][ni] = __builtin_amdgcn_mfma_f32_16x16x32_bf16(
                    af[mi][0], bfr[ni][0], acc[mi][ni], 0, 0, 0);
                acc[mi][ni] = __builtin_amdgcn_mfma_f32_16x16x32_bf16(
                    af[mi][1], bfr[ni][1], acc[mi][ni], 0, 0, 0);
            }
    }

    __syncthreads();                           // staging buffers free now
    const int r0 = (lane >> 4) * 4;

    if (mode == 1) {
        // fp32 + residual, two 64-row passes staged in LDS (32KB fp32)
        float* cf = (float*)lds;
#pragma unroll
        for (int p = 0; p < 2; ++p) {
            if ((wave >> 1) == p) {
#pragma unroll
                for (int ni = 0; ni < 4; ++ni) {
                    const int col = wn + ni * 16 + lrow;
                    const float bv = bias[n0 + col];
#pragma unroll
                    for (int mi = 0; mi < 4; ++mi)
#pragma unroll
                        for (int r = 0; r < 4; ++r) {
                            const int row = mi * 16 + r0 + r;       // 0..63
                            const int g = (col >> 2) ^ (((row >> 2) & 1) << 2);
                            cf[row * 128 + g * 4 + (col & 3)] = acc[mi][ni][r] + bv;
                        }
                }
            }
            __syncthreads();
#pragma unroll
            for (int i = 0; i < 8; ++i) {
                const int ci = i * 256 + tid;        // 16B chunk id
                const int row = ci >> 5, cg = ci & 31;
                const int g = cg ^ (((row >> 2) & 1) << 2);
                float4 v = *(const float4*)&cf[row * 128 + g * 4];
                const size_t gidx = (size_t)(m0 + p * 64 + row) * N + n0 + cg * 4;
                const float4 rz = *(const float4*)&resid[gidx];
                v.x += rz.x; v.y += rz.y; v.z += rz.z; v.w += rz.w;
                *(float4*)&outF[gidx] = v;
            }
            __syncthreads();
        }
    } else {
        // bf16 out (mode 0 plain / mode 2 gelu), full 128x128 tile in LDS
#pragma unroll
        for (int ni = 0; ni < 4; ++ni) {
            const int col = wn + ni * 16 + lrow;
            const float bv = bias[n0 + col];
#pragma unroll
            for (int mi = 0; mi < 4; ++mi)
#pragma unroll
                for (int r = 0; r < 4; ++r) {
                    const int row = wm + mi * 16 + r0 + r;
                    float v = acc[mi][ni][r] + bv;
                    if (mode == 2)
                        v = 0.5f * v * (1.0f + erff(v * 0.70710678118654752f));
                    const int g = (col >> 3) ^ (((row >> 2) & 3) << 1);
                    lds[row * 128 + g * 8 + (col & 7)] = bf16bits(v);
                }
        }
        __syncthreads();
#pragma unroll
        for (int i = 0; i < 8; ++i) {
            const int ci = i * 256 + tid;            // 16B chunk id
            const int row = ci >> 4, cg = ci & 15;
            const int g = cg ^ (((row >> 2) & 3) << 1);
            const bf16x8 v = *(const bf16x8*)&lds[row * 128 + g * 8];
            *(bf16x8*)&outB[(size_t)(m0 + row) * N + n0 + cg * 8] = v;
        }
    }
}

// ---------------------------------------------------------------------------
// Flash attention v4 (causal, balanced, 2 blocks/CU).
// Grid (8, 16, 4) = 512 blocks; block x does q-tiles (15-x) then (x), 128
// rows each -> uniform 34 K-tiles/block. 4 waves; wave owns 32 q-rows.
// K/V 64x64 tiles staged via global_load_lds, double-buffered, XOR-swizzled.
// Softmax natively exp2-domain (scale folded into Wq/bq); DPP reductions.
// ---------------------------------------------------------------------------
__global__ __launch_bounds__(256, 2) void attn_kernel(
    const uint16_t* __restrict__ qkv, const uint16_t* __restrict__ Vt,
    uint16_t* __restrict__ ctx)
{
    const int h = blockIdx.y, b = blockIdx.z;
    const int tid = threadIdx.x, wave = tid >> 6, lane = tid & 63;
    const int quad = lane >> 4, lcol = lane & 15, lr4 = quad * 4;
    const int sx = lcol & 7;
    const uint16_t* qbase = qkv + (size_t)b * 2048 * 3072;
    const uint16_t* kgb = qbase + 1024 + h * 64;
    const uint16_t* vtb = Vt + (size_t)(b * 16 + h) * 64 * 2048;

    __shared__ __align__(16) uint16_t kbuf[2][64 * 64];
    __shared__ __align__(16) uint16_t vbuf[2][64 * 64];
    __shared__ __align__(16) uint16_t pshm[4][32 * 64];

    const int rr = lane >> 3, sl = lane & 7;
    const int swz = sl ^ rr;                 // global 16B-chunk this lane fetches

#define STAGE(ktile, bb)                                                        \
    {                                                                           \
        const int _kb = (ktile) * 64;                                           \
        _Pragma("unroll")                                                       \
        for (int i = 0; i < 2; ++i) {                                           \
            const int j = wave * 2 + i;                                         \
            const int r = j * 8 + rr;                                           \
            gload_lds16(kgb + (size_t)(_kb + r) * 3072 + swz * 8,               \
                        &kbuf[bb][j * 512]);                                    \
            gload_lds16(vtb + (size_t)r * 2048 + _kb + swz * 8,                 \
                        &vbuf[bb][j * 512]);                                    \
        }                                                                       \
    }

    for (int pp = 0; pp < 2; ++pp) {
        const int qt = pp ? (int)blockIdx.x : 15 - (int)blockIdx.x;
        const int qr0 = qt * 128 + wave * 32;

        // Q fragments (A-layout): m = lcol, k = quad*8+j (+32 second chunk)
        bf16x8 qf[2][2];
#pragma unroll
        for (int mi = 0; mi < 2; ++mi) {
            const uint16_t* qp = qbase + (size_t)(qr0 + mi * 16 + lcol) * 3072 + h * 64;
            qf[mi][0] = *(const bf16x8*)(qp + quad * 8);
            qf[mi][1] = *(const bf16x8*)(qp + 32 + quad * 8);
        }

        floatx4 o[2][4] = {};
        float m_i[2][4], l_i[2][4];
#pragma unroll
        for (int mi = 0; mi < 2; ++mi)
#pragma unroll
            for (int r = 0; r < 4; ++r) { m_i[mi][r] = -1e30f; l_i[mi][r] = 0.f; }

        const int nk = 2 * qt + 2;
        __syncthreads();                       // prior pass done with buffers
        STAGE(0, 0);
        int cur = 0;

        for (int kt = 0; kt < nk; ++kt) {
            const int kb = kt * 64;
            __syncthreads();                   // drains vmcnt: buf[cur] ready
            if (kt + 1 < nk) STAGE(kt + 1, cur ^ 1);

            if (kb <= qr0 + 31) {              // wave-uniform causal skip
                bf16x8 kf[4][2];
#pragma unroll
                for (int nt = 0; nt < 4; ++nt) {
                    const int krow = nt * 16 + lcol;
                    kf[nt][0] = *(const bf16x8*)&kbuf[cur][krow * 64 + ((quad ^ sx) * 8)];
                    kf[nt][1] = *(const bf16x8*)&kbuf[cur][krow * 64 + (((quad + 4) ^ sx) * 8)];
                }
#pragma unroll
                for (int mi = 0; mi < 2; ++mi) {
                    floatx4 sv[4];
#pragma unroll
                    for (int nt = 0; nt < 4; ++nt) {
                        floatx4 s = {0.f, 0.f, 0.f, 0.f};
                        s = __builtin_amdgcn_mfma_f32_16x16x32_bf16(qf[mi][0], kf[nt][0], s, 0, 0, 0);
                        s = __builtin_amdgcn_mfma_f32_16x16x32_bf16(qf[mi][1], kf[nt][1], s, 0, 0, 0);
                        sv[nt] = s;
                    }
                    if (kb + 63 > qr0 + mi * 16) {     // causal mask needed
#pragma unroll
                        for (int nt = 0; nt < 4; ++nt)
#pragma unroll
                            for (int r = 0; r < 4; ++r) {
                                const int row = qr0 + mi * 16 + lr4 + r;
                                const int col = kb + nt * 16 + lcol;
                                if (col > row) sv[nt][r] = -1e30f;
                            }
                    }
#pragma unroll
                    for (int r = 0; r < 4; ++r) {
                        float m = fmaxf(fmaxf(sv[0][r], sv[1][r]),
                                        fmaxf(sv[2][r], sv[3][r]));
                        m = rowmax16(m);
                        const float mn = fmaxf(m_i[mi][r], m);
                        const float alpha = __builtin_amdgcn_exp2f(m_i[mi][r] - mn);
                        m_i[mi][r] = mn;
                        const int row = mi * 16 + lr4 + r;
                        const int rsw = row & 7;
                        float l = 0.f;
#pragma unroll
                        for (int nt = 0; nt < 4; ++nt) {
                            const float p = __builtin_amdgcn_exp2f(sv[nt][r] - mn);
                            l += p;
                            const int col = nt * 16 + lcol;
                            pshm[wave][row * 64 + (((col >> 3) ^ rsw) * 8) + (col & 7)] =
                                bf16bits(p);
                        }
                        l = rowsum16(l);
                        l_i[mi][r] = l_i[mi][r] * alpha + l;
#pragma unroll
                        for (int ht = 0; ht < 4; ++ht) o[mi][ht][r] *= alpha;
                    }
                }
                // P (A-layout) fragments from pshm
                bf16x8 pf[2][2];
#pragma unroll
                for (int mi = 0; mi < 2; ++mi) {
                    const int prow = mi * 16 + lcol;
                    pf[mi][0] = *(const bf16x8*)&pshm[wave][prow * 64 + ((quad ^ sx) * 8)];
                    pf[mi][1] = *(const bf16x8*)&pshm[wave][prow * 64 + (((quad + 4) ^ sx) * 8)];
                }
#pragma unroll
                for (int ht = 0; ht < 4; ++ht) {
                    const int hd = ht * 16 + lcol;
                    const bf16x8 vf0 = *(const bf16x8*)&vbuf[cur][hd * 64 + ((quad ^ sx) * 8)];
                    const bf16x8 vf1 = *(const bf16x8*)&vbuf[cur][hd * 64 + (((quad + 4) ^ sx) * 8)];
#pragma unroll
                    for (int mi = 0; mi < 2; ++mi) {
                        o[mi][ht] = __builtin_amdgcn_mfma_f32_16x16x32_bf16(pf[mi][0], vf0, o[mi][ht], 0, 0, 0);
                        o[mi][ht] = __builtin_amdgcn_mfma_f32_16x16x32_bf16(pf[mi][1], vf1, o[mi][ht], 0, 0, 0);
                    }
                }
            }
            cur ^= 1;
        }

#pragma unroll
        for (int mi = 0; mi < 2; ++mi)
#pragma unroll
            for (int r = 0; r < 4; ++r) {
                const float inv = 1.0f / l_i[mi][r];
                const int row = qr0 + mi * 16 + lr4 + r;
#pragma unroll
                for (int ht = 0; ht < 4; ++ht)
                    ctx[(size_t)(b * 2048 + row) * 1024 + h * 64 + ht * 16 + lcol] =
                        bf16bits(o[mi][ht][r] * inv);
            }
    }
#undef STAGE
}

// ---------------------------------------------------------------------------
// Launch
// ---------------------------------------------------------------------------
extern "C" void kernel_launch(void* const* d_in, const int* in_sizes, int n_in,
                              void* d_out, int out_size, void* d_ws, size_t ws_size,
                              hipStream_t stream)
{
    (void)in_sizes; (void)n_in; (void)out_size; (void)ws_size;
    const float* x     = (const float*)d_in[0];
    const float* ln1_g = (const float*)d_in[2];
    const float* ln1_b = (const float*)d_in[3];
    const float* Wq    = (const float*)d_in[4];
    const float* bq    = (const float*)d_in[5];
    const float* Wk    = (const float*)d_in[6];
    const float* bk    = (const float*)d_in[7];
    const float* Wv    = (const float*)d_in[8];
    const float* bv    = (const float*)d_in[9];
    const float* Wo    = (const float*)d_in[10];
    const float* bo    = (const float*)d_in[11];
    const float* ln2_g = (const float*)d_in[12];
    const float* ln2_b = (const float*)d_in[13];
    const float* W1    = (const float*)d_in[14];
    const float* b1    = (const float*)d_in[15];
    const float* W2    = (const float*)d_in[16];
    const float* b2    = (const float*)d_in[17];
    float* out = (float*)d_out;

    char* w = (char*)d_ws;
    uint16_t* Wqkv_t = (uint16_t*)w;  w += 6291456;    // [3072][1024]
    uint16_t* Wo_t   = (uint16_t*)w;  w += 2097152;    // [1024][1024]
    uint16_t* W1_t   = (uint16_t*)w;  w += 8388608;    // [4096][1024]
    uint16_t* W2_t   = (uint16_t*)w;  w += 8388608;    // [1024][4096]
    float*    bqkv   = (float*)w;     w += 16384;      // [3072]
    float*    x2     = (float*)w;     w += 33554432;   // [8192][1024] fp32
    char* region = w;
    uint16_t* hbuf = (uint16_t*)region;                        // 16MB h, later ctx
    uint16_t* qkv  = (uint16_t*)(region + 16777216);           // 48MB
    uint16_t* Vt   = (uint16_t*)(region + 16777216 + 50331648);// 16MB
    uint16_t* ctx  = hbuf;
    uint16_t* h2   = (uint16_t*)region;
    uint16_t* a1   = (uint16_t*)(region + 16777216);

    repack_qkv<<<dim3(32, 2, 48), 256, 0, stream>>>(Wq, Wk, Wv, Wqkv_t);
    transpose_f2b<<<dim3(32, 32),  256, 0, stream>>>(Wo, Wo_t, 1024, 1024);
    transpose_f2b<<<dim3(128, 32), 256, 0, stream>>>(W1, W1_t, 1024, 4096);
    transpose_f2b<<<dim3(32, 128), 256, 0, stream>>>(W2, W2_t, 4096, 1024);
    concat_bias<<<12, 256, 0, stream>>>(bq, bk, bv, bqkv);
    ln_bf16<<<8192, 256, 0, stream>>>(x, ln1_g, ln1_b, hbuf);
    gemm_bf16<<<dim3(24, 64), 256, 0, stream>>>(hbuf, Wqkv_t, 8192, 3072, 1024,
                                                bqkv, nullptr, nullptr, qkv, 0);
    transpose_v<<<dim3(64, 2, 64), 256, 0, stream>>>(qkv, Vt);
    attn_kernel<<<dim3(8, 16, 4), 256, 0, stream>>>(qkv, Vt, ctx);
    gemm_bf16<<<dim3(8, 64), 256, 0, stream>>>(ctx, Wo_t, 8192, 1024, 1024,
                                               bo, x, x2, nullptr, 1);
    ln_bf16<<<8192, 256, 0, stream>>>(x2, ln2_g, ln2_b, h2);
    gemm_bf16<<<dim3(32, 64), 256, 0, stream>>>(h2, W1_t, 8192, 4096, 1024,
                                                b1, nullptr, nullptr, a1, 2);
    gemm_bf16<<<dim3(8, 64), 256, 0, stream>>>(a1, W2_t, 8192, 1024, 4096,
                                               b2, x2, out, nullptr, 1);
}